// Round 1
// baseline (2309.851 us; speedup 1.0000x reference)
//
#include <hip/hip_runtime.h>
#include <hip/hip_bf16.h>
#include <stdint.h>

#define EMB 128

static constexpr int N_USER = 200000, N_VIDEO = 100000, N_PUB = 20000, N_TAG = 5000;
static constexpr int ROW_U = 0, ROW_V = 200000, ROW_P = 300000, ROW_T = 320000;
static constexpr int ROWS = 325000;           // total feature rows (u|v|p|t)
static constexpr int TOTAL_E = 7000000;       // all edges, all relations
static constexpr int TOTAL_GROUPS = 650000;   // sum of n_dst over 8 relations

// ---------- bf16 helpers (RNE pack, shift-expand unpack) ----------
__device__ inline unsigned bf16_rne(float f) {
  unsigned u = __float_as_uint(f);
  return (u + 0x7fffu + ((u >> 16) & 1u)) >> 16;
}
__device__ inline unsigned pack_bf16x2(float lo, float hi) {
  return bf16_rne(lo) | (bf16_rne(hi) << 16);
}

// ---------- descriptors (passed by value through kernarg) ----------
struct EdgeDesc {
  int cumE[9];            // edge prefix per relation
  int n_dst[8];
  const int* esrc[8];
  const int* edst[8];
  int* cur[8];            // counts -> scan cursor (same buffer)
  int* off[8];            // CSR offsets, n_dst+1
  int* sorted[8];         // src indices sorted by dst
};

struct AggrDesc {
  int cum[9];             // group (dst row) prefix per relation
  int src_base[8];        // row base of src node type in feature buffer
  int src_col[8];         // 0 or 64: which half of src feature to read
  int dst_base[8];        // row base of dst node type
  int dst_col[8];         // 0 or 64: which half of dst row this relation fills
  const int* off[8];
  const int* srcs[8];
};

// ---------- setup kernels (run once per call) ----------
__global__ void count_kernel(EdgeDesc d) {
  int i = blockIdx.x * blockDim.x + threadIdx.x;
  if (i >= d.cumE[8]) return;
  int r = 0;
#pragma unroll
  for (int k = 1; k < 8; ++k) if (i >= d.cumE[k]) r = k;
  atomicAdd(&d.cur[r][d.edst[r][i - d.cumE[r]]], 1);
}

// one block per relation: exclusive scan of counts -> off[], and re-init cur[] with same values
__global__ __launch_bounds__(1024) void scan_kernel(EdgeDesc d) {
  int r = blockIdx.x;
  int N = d.n_dst[r];
  int* cnt = d.cur[r];
  int* off = d.off[r];
  __shared__ int wsums[16];
  int tid = threadIdx.x;
  int L = (N + 1023) >> 10;
  int lo = min(tid * L, N);
  int hi = min(lo + L, N);
  int s = 0;
  for (int i = lo; i < hi; ++i) s += cnt[i];
  int lane = tid & 63, wv = tid >> 6;
  int v = s;
#pragma unroll
  for (int dd = 1; dd < 64; dd <<= 1) {
    int t = __shfl_up(v, dd);
    if (lane >= dd) v += t;
  }
  if (lane == 63) wsums[wv] = v;
  __syncthreads();
  if (tid < 16) {
    int x = wsums[tid];
#pragma unroll
    for (int dd = 1; dd < 16; dd <<= 1) {
      int t = __shfl_up(x, dd);
      if (tid >= dd) x += t;
    }
    wsums[tid] = x;
  }
  __syncthreads();
  int run = (wv ? wsums[wv - 1] : 0) + (v - s);   // exclusive prefix for this thread's chunk
  for (int i = lo; i < hi; ++i) {
    int c = cnt[i];
    off[i] = run;
    cnt[i] = run;       // cursor for scatter (same buffer as counts)
    run += c;
  }
  if (tid == 1023) off[N] = wsums[15];
}

__global__ void scatter_kernel(EdgeDesc d) {
  int i = blockIdx.x * blockDim.x + threadIdx.x;
  if (i >= d.cumE[8]) return;
  int r = 0;
#pragma unroll
  for (int k = 1; k < 8; ++k) if (i >= d.cumE[k]) r = k;
  int e = i - d.cumE[r];
  int dv = d.edst[r][e];
  int pos = atomicAdd(&d.cur[r][dv], 1);
  d.sorted[r][pos] = d.esrc[r][e];
}

// f32 inputs -> bf16 feature buffer (concatenated rows u|v|p|t)
__global__ void convert_kernel(const float* __restrict__ u, const float* __restrict__ v,
                               const float* __restrict__ p, const float* __restrict__ t,
                               uint16_t* __restrict__ feat) {
  int idx = blockIdx.x * blockDim.x + threadIdx.x;
  const int total4 = ROWS * EMB / 4;
  if (idx >= total4) return;
  int flat = idx * 4;
  int row = flat >> 7;
  int col = flat & 127;
  const float* s;
  if (row < ROW_V)      s = u + (size_t)row * EMB + col;
  else if (row < ROW_P) s = v + (size_t)(row - ROW_V) * EMB + col;
  else if (row < ROW_T) s = p + (size_t)(row - ROW_P) * EMB + col;
  else                  s = t + (size_t)(row - ROW_T) * EMB + col;
  float4 f = *(const float4*)s;
  uint2 o;
  o.x = pack_bf16x2(f.x, f.y);
  o.y = pack_bf16x2(f.z, f.w);
  *(uint2*)(feat + flat) = o;
}

// ---------- hot kernel: one 16-lane group per (relation, dst row) ----------
// Each lane owns 4 consecutive bf16 of the 64-wide half (16 lanes x 8B = 128B/edge, coalesced).
__global__ __launch_bounds__(256) void aggr_kernel(AggrDesc d, const uint16_t* __restrict__ prev,
                                                   uint16_t* __restrict__ next,
                                                   float* __restrict__ out, float w) {
  int g = blockIdx.x * 16 + (threadIdx.x >> 4);
  if (g >= d.cum[8]) return;
  int lane = threadIdx.x & 15;
  int r = 0;
#pragma unroll
  for (int k = 1; k < 8; ++k) if (g >= d.cum[k]) r = k;
  int n = g - d.cum[r];
  const int* __restrict__ off = d.off[r];
  int beg = off[n], end = off[n + 1];
  int deg = end - beg;
  float recip = 1.0f / (float)(deg > 0 ? deg : 1);
  const int* __restrict__ srcs = d.srcs[r];
  const uint16_t* sbase = prev + (size_t)d.src_base[r] * EMB + d.src_col[r] + lane * 4;
  float a0 = 0.f, a1 = 0.f, a2 = 0.f, a3 = 0.f;
  for (int e = beg; e < end; ++e) {
    int s = srcs[e];
    uint2 q = *(const uint2*)(sbase + (size_t)s * EMB);
    a0 += __uint_as_float(q.x << 16);
    a1 += __uint_as_float(q.x & 0xffff0000u);
    a2 += __uint_as_float(q.y << 16);
    a3 += __uint_as_float(q.y & 0xffff0000u);
  }
  a0 *= recip; a1 *= recip; a2 *= recip; a3 *= recip;
  size_t dpos = (size_t)(d.dst_base[r] + n) * EMB + d.dst_col[r] + lane * 4;
  uint2 ov;
  ov.x = pack_bf16x2(a0, a1);
  ov.y = pack_bf16x2(a2, a3);
  *(uint2*)(next + dpos) = ov;            // becomes next layer's input (bf16)
  float4* po = (float4*)(out + dpos);     // prefix accumulation in f32
  float4 vv = *po;
  vv.x += w * a0; vv.y += w * a1; vv.z += w * a2; vv.w += w * a3;
  *po = vv;
}

// ---------- host ----------
extern "C" void kernel_launch(void* const* d_in, const int* in_sizes, int n_in,
                              void* d_out, int out_size, void* d_ws, size_t ws_size,
                              hipStream_t stream) {
  const float* emb_u = (const float*)d_in[0];
  const float* emb_v = (const float*)d_in[1];
  const float* emb_p = (const float*)d_in[2];
  const float* emb_t = (const float*)d_in[3];

  // relations in load-balance order (descending avg degree) so long-running
  // groups (tag: deg~160) are scheduled first.
  // {src_in_idx, dst_in_idx, E, n_dst, src_base, src_col, dst_base, dst_col}
  struct RelInfo { int si, di, E, n_dst, src_base, src_col, dst_base, dst_col; };
  const RelInfo rels[8] = {
    {12, 13,  800000, N_TAG,   ROW_V, 64, ROW_T,  0},  // vt: v[:,64:] -> tag cols 0..63
    {16, 17,  400000, N_TAG,   ROW_P, 64, ROW_T, 64},  // pt
    { 8,  9,  800000, N_PUB,   ROW_U, 64, ROW_P,  0},  // up
    {18, 19,  400000, N_PUB,   ROW_T, 64, ROW_P, 64},  // tp
    { 4,  5, 1500000, N_VIDEO, ROW_U,  0, ROW_V,  0},  // uv
    {14, 15,  800000, N_VIDEO, ROW_T,  0, ROW_V, 64},  // tv
    { 6,  7, 1500000, N_USER,  ROW_V,  0, ROW_U,  0},  // vu
    {10, 11,  800000, N_USER,  ROW_P,  0, ROW_U, 64},  // pu
  };

  // ---- workspace layout (~200 MB): featA | featB | off[8] | cur[8] | sorted[8]
  char* ws = (char*)d_ws;
  size_t cursor = 0;
  auto take = [&](size_t bytes) -> char* {
    char* p = ws + cursor;
    cursor = (cursor + bytes + 255) & ~(size_t)255;
    return p;
  };
  uint16_t* featA = (uint16_t*)take((size_t)ROWS * EMB * 2);
  uint16_t* featB = (uint16_t*)take((size_t)ROWS * EMB * 2);
  int* offp[8];
  for (int r = 0; r < 8; ++r) offp[r] = (int*)take((size_t)(rels[r].n_dst + 1) * 4);
  char* cur_region = ws + cursor;
  int* curp[8];
  for (int r = 0; r < 8; ++r) curp[r] = (int*)take((size_t)rels[r].n_dst * 4);
  size_t cur_bytes = (size_t)((ws + cursor) - cur_region);
  int* sortp[8];
  for (int r = 0; r < 8; ++r) sortp[r] = (int*)take((size_t)rels[r].E * 4);

  // ---- descriptors
  EdgeDesc ed;
  AggrDesc ad;
  int eacc = 0, gacc = 0;
  for (int r = 0; r < 8; ++r) {
    ed.cumE[r] = eacc; eacc += rels[r].E;
    ed.n_dst[r] = rels[r].n_dst;
    ed.esrc[r] = (const int*)d_in[rels[r].si];
    ed.edst[r] = (const int*)d_in[rels[r].di];
    ed.cur[r] = curp[r];
    ed.off[r] = offp[r];
    ed.sorted[r] = sortp[r];

    ad.cum[r] = gacc; gacc += rels[r].n_dst;
    ad.src_base[r] = rels[r].src_base;
    ad.src_col[r] = rels[r].src_col;
    ad.dst_base[r] = rels[r].dst_base;
    ad.dst_col[r] = rels[r].dst_col;
    ad.off[r] = offp[r];
    ad.srcs[r] = sortp[r];
  }
  ed.cumE[8] = eacc;   // 7,000,000
  ad.cum[8] = gacc;    // 650,000

  // ---- CSR build (per call; reused across 3 layers)
  hipMemsetAsync(cur_region, 0, cur_bytes, stream);
  count_kernel<<<(TOTAL_E + 255) / 256, 256, 0, stream>>>(ed);
  scan_kernel<<<8, 1024, 0, stream>>>(ed);
  scatter_kernel<<<(TOTAL_E + 255) / 256, 256, 0, stream>>>(ed);

  // ---- feature init: featA = bf16(inputs); d_out = f32 inputs (prefix base)
  convert_kernel<<<(ROWS * EMB / 4 + 255) / 256, 256, 0, stream>>>(emb_u, emb_v, emb_p, emb_t, featA);
  float* out = (float*)d_out;
  hipMemcpyAsync(out,                 emb_u, (size_t)N_USER  * EMB * 4, hipMemcpyDeviceToDevice, stream);
  hipMemcpyAsync(out + (size_t)ROW_V * EMB, emb_v, (size_t)N_VIDEO * EMB * 4, hipMemcpyDeviceToDevice, stream);
  hipMemcpyAsync(out + (size_t)ROW_P * EMB, emb_p, (size_t)N_PUB   * EMB * 4, hipMemcpyDeviceToDevice, stream);
  hipMemcpyAsync(out + (size_t)ROW_T * EMB, emb_t, (size_t)N_TAG   * EMB * 4, hipMemcpyDeviceToDevice, stream);

  // ---- 3 layers, ping-pong bf16 feature buffers
  uint16_t* prev = featA;
  uint16_t* next = featB;
  const int aggr_blocks = (TOTAL_GROUPS * 16 + 255) / 256;
  for (int layer = 0; layer < 3; ++layer) {
    float w = 1.0f / (float)(layer + 2);
    aggr_kernel<<<aggr_blocks, 256, 0, stream>>>(ad, prev, next, out, w);
    uint16_t* tmp = prev; prev = next; next = tmp;
  }
}

// Round 2
// 731.420 us; speedup vs baseline: 3.1580x; 3.1580x over previous
//
#include <hip/hip_runtime.h>
#include <hip/hip_bf16.h>
#include <stdint.h>

#define EMB 128
#define CAP 12288          // max edges per bucket (avg <=8192, sigma ~90 -> huge margin)

static constexpr int N_USER = 200000, N_VIDEO = 100000, N_PUB = 20000, N_TAG = 5000;
static constexpr int ROW_U = 0, ROW_V = 200000, ROW_P = 300000, ROW_T = 320000;
static constexpr int ROWS = 325000;
static constexpr int TOTAL_E = 7000000;
static constexpr int TOTAL_GROUPS = 650000;
static constexpr int TILE = 4096;

// ---------- bf16 helpers ----------
__device__ inline unsigned bf16_rne(float f) {
  unsigned u = __float_as_uint(f);
  return (u + 0x7fffu + ((u >> 16) & 1u)) >> 16;
}
__device__ inline unsigned pack_bf16x2(float lo, float hi) {
  return bf16_rne(lo) | (bf16_rne(hi) << 16);
}

// ---------- descriptors ----------
struct SortDesc {
  int tcum[9];            // tile prefix per relation
  int bcum[9];            // bucket prefix per relation
  int gcum[8];            // group (dst row) prefix per relation
  int E[8];
  int n_dst[8];
  int wshift[8];          // log2(dsts per bucket)
  const int* esrc[8];
  const int* edst[8];
};

struct AggrDesc {
  int cum[9];
  int src_base[8];
  int src_col[8];
  int dst_base[8];
  int dst_col[8];
  const float* demb[8];   // f32 input emb of dst node type (layer-0 base)
};

// ---------- pass 1: bin edges into dst-range buckets ----------
__global__ __launch_bounds__(256) void part_kernel(SortDesc d, uint2* __restrict__ pairs,
                                                   int* __restrict__ cursors) {
  __shared__ int cnt[256];
  __shared__ int lcur[256];
  int blk = blockIdx.x;
  int r = 0;
#pragma unroll
  for (int k = 1; k < 8; ++k) if (blk >= d.tcum[k]) r = k;
  int base = (blk - d.tcum[r]) * TILE;
  int n = min(TILE, d.E[r] - base);
  const int* __restrict__ esrc = d.esrc[r];
  const int* __restrict__ edst = d.edst[r];
  int tid = threadIdx.x;
  int B = d.bcum[r + 1] - d.bcum[r];
  int sh = d.wshift[r];
  int bb = d.bcum[r];
  if (tid < B) cnt[tid] = 0;
  __syncthreads();
  for (int i = tid; i < n; i += 256)
    atomicAdd(&cnt[edst[base + i] >> sh], 1);
  __syncthreads();
  if (tid < B) {
    int c = cnt[tid];
    lcur[tid] = c ? atomicAdd(&cursors[bb + tid], c) : 0;
  }
  __syncthreads();
  for (int i = tid; i < n; i += 256) {
    int dv = edst[base + i];
    int sv = esrc[base + i];
    int b = dv >> sh;
    int pos = atomicAdd(&lcur[b], 1);
    if (pos < CAP) {
      uint2 pr; pr.x = (unsigned)sv; pr.y = (unsigned)dv;
      pairs[(size_t)(bb + b) * CAP + pos] = pr;
    }
  }
}

// ---------- exclusive scan over bucket counts -> bucket bases ----------
__global__ __launch_bounds__(256) void bases_kernel(const int* __restrict__ cursors,
                                                    int* __restrict__ bases, int NB) {
  __shared__ int wsums[4];
  int tid = threadIdx.x;
  int L = (NB + 255) / 256;
  int lo = min(tid * L, NB), hi = min(lo + L, NB);
  int s = 0;
  for (int i = lo; i < hi; ++i) s += cursors[i];
  int lane = tid & 63, wv = tid >> 6;
  int v = s;
#pragma unroll
  for (int dd = 1; dd < 64; dd <<= 1) {
    int t = __shfl_up(v, dd);
    if (lane >= dd) v += t;
  }
  if (lane == 63) wsums[wv] = v;
  __syncthreads();
  if (tid == 0) {
    int run = 0;
#pragma unroll
    for (int k = 0; k < 4; ++k) { int t = wsums[k]; wsums[k] = run; run += t; }
  }
  __syncthreads();
  int run = wsums[wv] + (v - s);
  for (int i = lo; i < hi; ++i) { int c = cursors[i]; bases[i] = run; run += c; }
}

// ---------- pass 2: per-bucket counting sort in LDS, coalesced writeout ----------
__global__ __launch_bounds__(256) void build_kernel(SortDesc d, const uint2* __restrict__ pairs,
                                                    const int* __restrict__ cursors,
                                                    const int* __restrict__ bases,
                                                    int* __restrict__ sorted,
                                                    int* __restrict__ Beg, int* __restrict__ Deg) {
  __shared__ int cnt[1024];
  __shared__ int stage[CAP];
  __shared__ int wsums[4];
  int bucket = blockIdx.x;
  int r = 0;
#pragma unroll
  for (int k = 1; k < 8; ++k) if (bucket >= d.bcum[k]) r = k;
  int bl = bucket - d.bcum[r];
  int sh = d.wshift[r];
  int first = bl << sh;
  int Wa = min(1 << sh, d.n_dst[r] - first);
  int tid = threadIdx.x;
  int n_b = min(cursors[bucket], CAP);
  int gbase = bases[bucket];
  const uint2* __restrict__ bp = pairs + (size_t)bucket * CAP;

  for (int i = tid; i < 1024; i += 256) cnt[i] = 0;
  __syncthreads();
  for (int i = tid; i < n_b; i += 256)
    atomicAdd(&cnt[(int)bp[i].y - first], 1);
  __syncthreads();

  // block exclusive scan of cnt[0..1024), 4 per thread
  int t4 = tid * 4;
  int c0 = cnt[t4], c1 = cnt[t4 + 1], c2 = cnt[t4 + 2], c3 = cnt[t4 + 3];
  int s = c0 + c1 + c2 + c3;
  int lane = tid & 63, wv = tid >> 6;
  int v = s;
#pragma unroll
  for (int dd = 1; dd < 64; dd <<= 1) {
    int t = __shfl_up(v, dd);
    if (lane >= dd) v += t;
  }
  if (lane == 63) wsums[wv] = v;
  __syncthreads();
  if (tid == 0) {
    int run = 0;
#pragma unroll
    for (int k = 0; k < 4; ++k) { int t = wsums[k]; wsums[k] = run; run += t; }
  }
  __syncthreads();
  int ex = wsums[wv] + (v - s);
  int o0 = ex, o1 = ex + c0, o2 = o1 + c1, o3 = o2 + c2;
  cnt[t4] = o0; cnt[t4 + 1] = o1; cnt[t4 + 2] = o2; cnt[t4 + 3] = o3;
  // per-dst [beg,deg) for the aggregation kernel
  int g0 = d.gcum[r] + first + t4;
  if (t4 + 0 < Wa) { Beg[g0 + 0] = gbase + o0; Deg[g0 + 0] = c0; }
  if (t4 + 1 < Wa) { Beg[g0 + 1] = gbase + o1; Deg[g0 + 1] = c1; }
  if (t4 + 2 < Wa) { Beg[g0 + 2] = gbase + o2; Deg[g0 + 2] = c2; }
  if (t4 + 3 < Wa) { Beg[g0 + 3] = gbase + o3; Deg[g0 + 3] = c3; }
  __syncthreads();

  for (int i = tid; i < n_b; i += 256) {
    uint2 pr = bp[i];
    int pos = atomicAdd(&cnt[(int)pr.y - first], 1);
    stage[pos] = (int)pr.x;
  }
  __syncthreads();
  for (int i = tid; i < n_b; i += 256)
    sorted[gbase + i] = stage[i];
}

// ---------- f32 inputs -> bf16 feature buffer ----------
__global__ void convert_kernel(const float* __restrict__ u, const float* __restrict__ v,
                               const float* __restrict__ p, const float* __restrict__ t,
                               uint16_t* __restrict__ feat) {
  int idx = blockIdx.x * blockDim.x + threadIdx.x;
  const int total4 = ROWS * EMB / 4;
  if (idx >= total4) return;
  int flat = idx * 4;
  int row = flat >> 7;
  int col = flat & 127;
  const float* s;
  if (row < ROW_V)      s = u + (size_t)row * EMB + col;
  else if (row < ROW_P) s = v + (size_t)(row - ROW_V) * EMB + col;
  else if (row < ROW_T) s = p + (size_t)(row - ROW_P) * EMB + col;
  else                  s = t + (size_t)(row - ROW_T) * EMB + col;
  float4 f = *(const float4*)s;
  uint2 o;
  o.x = pack_bf16x2(f.x, f.y);
  o.y = pack_bf16x2(f.z, f.w);
  *(uint2*)(feat + flat) = o;
}

// ---------- hot kernel: one 8-lane group per (relation, dst row half) ----------
#define ACC(q) \
  a0 += __uint_as_float((q).x << 16); a1 += __uint_as_float((q).x & 0xffff0000u); \
  a2 += __uint_as_float((q).y << 16); a3 += __uint_as_float((q).y & 0xffff0000u); \
  a4 += __uint_as_float((q).z << 16); a5 += __uint_as_float((q).z & 0xffff0000u); \
  a6 += __uint_as_float((q).w << 16); a7 += __uint_as_float((q).w & 0xffff0000u);

__global__ __launch_bounds__(256) void aggr_kernel(AggrDesc d, const uint16_t* __restrict__ prev,
                                                   uint16_t* __restrict__ next,
                                                   float* __restrict__ out, float w,
                                                   int layer0, int writeNext,
                                                   const int* __restrict__ sorted,
                                                   const int* __restrict__ Beg,
                                                   const int* __restrict__ Deg) {
  int g = blockIdx.x * 32 + (threadIdx.x >> 3);
  if (g >= TOTAL_GROUPS) return;
  int lane = threadIdx.x & 7;
  int r = 0;
#pragma unroll
  for (int k = 1; k < 8; ++k) if (g >= d.cum[k]) r = k;
  int n = g - d.cum[r];
  int beg = Beg[g], dg = Deg[g];
  float recip = 1.0f / (float)(dg > 0 ? dg : 1);
  const uint16_t* sbase = prev + (size_t)d.src_base[r] * EMB + d.src_col[r] + lane * 8;
  float a0 = 0.f, a1 = 0.f, a2 = 0.f, a3 = 0.f, a4 = 0.f, a5 = 0.f, a6 = 0.f, a7 = 0.f;
  int e = beg, end = beg + dg;
  for (; e + 4 <= end; e += 4) {
    int s0 = sorted[e], s1 = sorted[e + 1], s2 = sorted[e + 2], s3 = sorted[e + 3];
    uint4 q0 = *(const uint4*)(sbase + (size_t)s0 * EMB);
    uint4 q1 = *(const uint4*)(sbase + (size_t)s1 * EMB);
    uint4 q2 = *(const uint4*)(sbase + (size_t)s2 * EMB);
    uint4 q3 = *(const uint4*)(sbase + (size_t)s3 * EMB);
    ACC(q0); ACC(q1); ACC(q2); ACC(q3);
  }
  for (; e < end; ++e) {
    int s0 = sorted[e];
    uint4 q = *(const uint4*)(sbase + (size_t)s0 * EMB);
    ACC(q);
  }
  a0 *= recip; a1 *= recip; a2 *= recip; a3 *= recip;
  a4 *= recip; a5 *= recip; a6 *= recip; a7 *= recip;

  int col = d.dst_col[r] + lane * 8;
  size_t dpos = (size_t)(d.dst_base[r] + n) * EMB + col;
  if (writeNext) {
    uint4 ov;
    ov.x = pack_bf16x2(a0, a1);
    ov.y = pack_bf16x2(a2, a3);
    ov.z = pack_bf16x2(a4, a5);
    ov.w = pack_bf16x2(a6, a7);
    *(uint4*)(next + dpos) = ov;
  }
  float4 v0, v1;
  if (layer0) {
    const float* de = d.demb[r] + (size_t)n * EMB + col;
    v0 = *(const float4*)de;
    v1 = *((const float4*)de + 1);
  } else {
    v0 = *(const float4*)(out + dpos);
    v1 = *((const float4*)(out + dpos) + 1);
  }
  v0.x += w * a0; v0.y += w * a1; v0.z += w * a2; v0.w += w * a3;
  v1.x += w * a4; v1.y += w * a5; v1.z += w * a6; v1.w += w * a7;
  *(float4*)(out + dpos) = v0;
  *((float4*)(out + dpos) + 1) = v1;
}

// ---------- host ----------
extern "C" void kernel_launch(void* const* d_in, const int* in_sizes, int n_in,
                              void* d_out, int out_size, void* d_ws, size_t ws_size,
                              hipStream_t stream) {
  const float* emb_u = (const float*)d_in[0];
  const float* emb_v = (const float*)d_in[1];
  const float* emb_p = (const float*)d_in[2];
  const float* emb_t = (const float*)d_in[3];

  // {src_idx, dst_idx, E, n_dst, src_base, src_col, dst_base, dst_col, wshift}
  struct RelInfo { int si, di, E, n_dst, src_base, src_col, dst_base, dst_col, wshift; };
  const RelInfo rels[8] = {
    {12, 13,  800000, N_TAG,   ROW_V, 64, ROW_T,  0,  5},  // vt
    {16, 17,  400000, N_TAG,   ROW_P, 64, ROW_T, 64,  5},  // pt
    { 8,  9,  800000, N_PUB,   ROW_U, 64, ROW_P,  0,  7},  // up
    {18, 19,  400000, N_PUB,   ROW_T, 64, ROW_P, 64,  7},  // tp
    { 4,  5, 1500000, N_VIDEO, ROW_U,  0, ROW_V,  0,  9},  // uv
    {14, 15,  800000, N_VIDEO, ROW_T,  0, ROW_V, 64,  9},  // tv
    { 6,  7, 1500000, N_USER,  ROW_V,  0, ROW_U,  0, 10},  // vu
    {10, 11,  800000, N_PUB ,  ROW_P,  0, ROW_U, 64, 10},  // pu (n_dst fixed below)
  };
  const float* dembs[8] = {emb_t, emb_t, emb_p, emb_p, emb_v, emb_v, emb_u, emb_u};

  // ---- ws layout: featA | featB | sorted | Beg | Deg | cursors | bases
  // pairs (139MB) aliases featA+featB (consumed before convert_kernel writes featA)
  char* ws = (char*)d_ws;
  size_t cursor = 0;
  auto take = [&](size_t bytes) -> char* {
    char* p = ws + cursor;
    cursor = (cursor + bytes + 255) & ~(size_t)255;
    return p;
  };
  uint16_t* featA = (uint16_t*)take((size_t)ROWS * EMB * 2);
  uint16_t* featB = (uint16_t*)take((size_t)ROWS * EMB * 2);
  int* sorted = (int*)take((size_t)TOTAL_E * 4);
  int* Beg    = (int*)take((size_t)TOTAL_GROUPS * 4);
  int* Deg    = (int*)take((size_t)TOTAL_GROUPS * 4);
  uint2* pairs = (uint2*)d_ws;   // alias

  SortDesc sd;
  AggrDesc ad;
  int tacc = 0, bacc = 0, gacc = 0;
  for (int r = 0; r < 8; ++r) {
    int n_dst = (r == 7) ? N_USER : rels[r].n_dst;   // pu dst = user
    sd.tcum[r] = tacc; tacc += (rels[r].E + TILE - 1) / TILE;
    sd.bcum[r] = bacc; bacc += (n_dst + (1 << rels[r].wshift) - 1) >> rels[r].wshift;
    sd.gcum[r] = gacc;
    sd.E[r] = rels[r].E;
    sd.n_dst[r] = n_dst;
    sd.wshift[r] = rels[r].wshift;
    sd.esrc[r] = (const int*)d_in[rels[r].si];
    sd.edst[r] = (const int*)d_in[rels[r].di];

    ad.cum[r] = gacc;
    ad.src_base[r] = rels[r].src_base;
    ad.src_col[r] = rels[r].src_col;
    ad.dst_base[r] = rels[r].dst_base;
    ad.dst_col[r] = rels[r].dst_col;
    ad.demb[r] = dembs[r];
    gacc += n_dst;
  }
  sd.tcum[8] = tacc;   // 1714 tiles
  sd.bcum[8] = bacc;   // 1412 buckets
  ad.cum[8] = gacc;    // 650000 groups

  int* cursors = (int*)take((size_t)bacc * 4);
  int* bases   = (int*)take((size_t)bacc * 4);

  // ---- CSR build
  hipMemsetAsync(cursors, 0, (size_t)bacc * 4, stream);
  part_kernel<<<tacc, 256, 0, stream>>>(sd, pairs, cursors);
  bases_kernel<<<1, 256, 0, stream>>>(cursors, bases, bacc);
  build_kernel<<<bacc, 256, 0, stream>>>(sd, pairs, cursors, bases, sorted, Beg, Deg);

  // ---- bf16 feature init (after pairs region is dead)
  convert_kernel<<<(ROWS * EMB / 4 + 255) / 256, 256, 0, stream>>>(emb_u, emb_v, emb_p, emb_t, featA);

  // ---- 3 layers
  float* out = (float*)d_out;
  uint16_t* prev = featA;
  uint16_t* next = featB;
  const int aggr_blocks = (TOTAL_GROUPS + 31) / 32;
  for (int layer = 0; layer < 3; ++layer) {
    float w = 1.0f / (float)(layer + 2);
    aggr_kernel<<<aggr_blocks, 256, 0, stream>>>(ad, prev, next, out, w,
                                                 layer == 0 ? 1 : 0, layer < 2 ? 1 : 0,
                                                 sorted, Beg, Deg);
    uint16_t* tmp = prev; prev = next; next = tmp;
  }
}

// Round 3
// 639.541 us; speedup vs baseline: 3.6117x; 1.1437x over previous
//
#include <hip/hip_runtime.h>
#include <hip/hip_bf16.h>
#include <stdint.h>

#define EMB 128
#define CAP 12288          // max edges per bucket (avg <=7700, huge margin)

static constexpr int N_USER = 200000, N_VIDEO = 100000, N_PUB = 20000, N_TAG = 5000;
static constexpr int ROW_U = 0, ROW_V = 200000, ROW_P = 300000, ROW_T = 320000;
static constexpr int ROWS = 325000;
static constexpr int TOTAL_E = 7000000;
static constexpr int TOTAL_GROUPS = 650000;
static constexpr int TILE = 4096;

// ---------- bf16 helpers ----------
__device__ inline unsigned bf16_rne(float f) {
  unsigned u = __float_as_uint(f);
  return (u + 0x7fffu + ((u >> 16) & 1u)) >> 16;
}
__device__ inline unsigned pack_bf16x2(float lo, float hi) {
  return bf16_rne(lo) | (bf16_rne(hi) << 16);
}

// ---------- descriptors ----------
struct SortDesc {
  int tcum[9];            // tile prefix per relation
  int bcum[9];            // bucket prefix per relation
  int gcum[8];            // group (dst row) prefix per relation
  int E[8];
  int n_dst[8];
  int wshift[8];          // log2(dsts per bucket)
  const int* esrc[8];
  const int* edst[8];
};

struct AggrDesc {
  int cum[9];
  int src_base[8];
  int src_col[8];
  int dst_base[8];
  int dst_col[8];
  const float* demb[8];   // f32 input emb of dst node type (final epilogue)
};

// ---------- pass 1: bin edges into dst-range buckets (packed 4B pairs) ----------
__global__ __launch_bounds__(256) void part_kernel(SortDesc d, unsigned* __restrict__ pairs,
                                                   int* __restrict__ cursors) {
  __shared__ int cnt[256];
  __shared__ int lcur[256];
  int blk = blockIdx.x;
  int r = 0;
#pragma unroll
  for (int k = 1; k < 8; ++k) if (blk >= d.tcum[k]) r = k;
  int base = (blk - d.tcum[r]) * TILE;
  int n = min(TILE, d.E[r] - base);
  const int* __restrict__ esrc = d.esrc[r];
  const int* __restrict__ edst = d.edst[r];
  int tid = threadIdx.x;
  int B = d.bcum[r + 1] - d.bcum[r];
  int sh = d.wshift[r];
  int msk = (1 << sh) - 1;
  int bb = d.bcum[r];
  if (tid < B) cnt[tid] = 0;
  __syncthreads();
  for (int i = tid; i < n; i += 256)
    atomicAdd(&cnt[edst[base + i] >> sh], 1);
  __syncthreads();
  if (tid < B) {
    int c = cnt[tid];
    lcur[tid] = c ? atomicAdd(&cursors[bb + tid], c) : 0;
  }
  __syncthreads();
  for (int i = tid; i < n; i += 256) {
    int dv = edst[base + i];
    int sv = esrc[base + i];
    int b = dv >> sh;
    int pos = atomicAdd(&lcur[b], 1);
    if (pos < CAP)
      pairs[(size_t)(bb + b) * CAP + pos] = ((unsigned)(dv & msk) << 18) | (unsigned)sv;
  }
}

// ---------- exclusive scan over bucket counts -> bucket bases ----------
__global__ __launch_bounds__(256) void bases_kernel(const int* __restrict__ cursors,
                                                    int* __restrict__ bases, int NB) {
  __shared__ int wsums[4];
  int tid = threadIdx.x;
  int L = (NB + 255) / 256;
  int lo = min(tid * L, NB), hi = min(lo + L, NB);
  int s = 0;
  for (int i = lo; i < hi; ++i) s += cursors[i];
  int lane = tid & 63, wv = tid >> 6;
  int v = s;
#pragma unroll
  for (int dd = 1; dd < 64; dd <<= 1) {
    int t = __shfl_up(v, dd);
    if (lane >= dd) v += t;
  }
  if (lane == 63) wsums[wv] = v;
  __syncthreads();
  if (tid == 0) {
    int run = 0;
#pragma unroll
    for (int k = 0; k < 4; ++k) { int t = wsums[k]; wsums[k] = run; run += t; }
  }
  __syncthreads();
  int run = wsums[wv] + (v - s);
  for (int i = lo; i < hi; ++i) { int c = cursors[i]; bases[i] = run; run += c; }
}

// ---------- pass 2: per-bucket counting sort in LDS, coalesced writeout ----------
__global__ __launch_bounds__(256) void build_kernel(SortDesc d, const unsigned* __restrict__ pairs,
                                                    const int* __restrict__ cursors,
                                                    const int* __restrict__ bases,
                                                    int* __restrict__ sorted,
                                                    int* __restrict__ Beg, int* __restrict__ Deg) {
  __shared__ int cnt[1024];
  __shared__ int stage[CAP];
  __shared__ int wsums[4];
  int bucket = blockIdx.x;
  int r = 0;
#pragma unroll
  for (int k = 1; k < 8; ++k) if (bucket >= d.bcum[k]) r = k;
  int bl = bucket - d.bcum[r];
  int sh = d.wshift[r];
  int first = bl << sh;
  int Wa = min(1 << sh, d.n_dst[r] - first);
  int tid = threadIdx.x;
  int n_b = min(cursors[bucket], CAP);
  int gbase = bases[bucket];
  const unsigned* __restrict__ bp = pairs + (size_t)bucket * CAP;

  for (int i = tid; i < 1024; i += 256) cnt[i] = 0;
  __syncthreads();
  for (int i = tid; i < n_b; i += 256)
    atomicAdd(&cnt[bp[i] >> 18], 1);
  __syncthreads();

  // block exclusive scan of cnt[0..1024), 4 per thread
  int t4 = tid * 4;
  int c0 = cnt[t4], c1 = cnt[t4 + 1], c2 = cnt[t4 + 2], c3 = cnt[t4 + 3];
  int s = c0 + c1 + c2 + c3;
  int lane = tid & 63, wv = tid >> 6;
  int v = s;
#pragma unroll
  for (int dd = 1; dd < 64; dd <<= 1) {
    int t = __shfl_up(v, dd);
    if (lane >= dd) v += t;
  }
  if (lane == 63) wsums[wv] = v;
  __syncthreads();
  if (tid == 0) {
    int run = 0;
#pragma unroll
    for (int k = 0; k < 4; ++k) { int t = wsums[k]; wsums[k] = run; run += t; }
  }
  __syncthreads();
  int ex = wsums[wv] + (v - s);
  int o0 = ex, o1 = ex + c0, o2 = o1 + c1, o3 = o2 + c2;
  cnt[t4] = o0; cnt[t4 + 1] = o1; cnt[t4 + 2] = o2; cnt[t4 + 3] = o3;
  int g0 = d.gcum[r] + first + t4;
  if (t4 + 0 < Wa) { Beg[g0 + 0] = gbase + o0; Deg[g0 + 0] = c0; }
  if (t4 + 1 < Wa) { Beg[g0 + 1] = gbase + o1; Deg[g0 + 1] = c1; }
  if (t4 + 2 < Wa) { Beg[g0 + 2] = gbase + o2; Deg[g0 + 2] = c2; }
  if (t4 + 3 < Wa) { Beg[g0 + 3] = gbase + o3; Deg[g0 + 3] = c3; }
  __syncthreads();

  for (int i = tid; i < n_b; i += 256) {
    unsigned pr = bp[i];
    int pos = atomicAdd(&cnt[pr >> 18], 1);
    stage[pos] = (int)(pr & 0x3FFFFu);
  }
  __syncthreads();
  for (int i = tid; i < n_b; i += 256)
    sorted[gbase + i] = stage[i];
}

// ---------- f32 inputs -> bf16 feature buffer ----------
__global__ void convert_kernel(const float* __restrict__ u, const float* __restrict__ v,
                               const float* __restrict__ p, const float* __restrict__ t,
                               uint16_t* __restrict__ feat) {
  int idx = blockIdx.x * blockDim.x + threadIdx.x;
  const int total4 = ROWS * EMB / 4;
  if (idx >= total4) return;
  int flat = idx * 4;
  int row = flat >> 7;
  int col = flat & 127;
  const float* s;
  if (row < ROW_V)      s = u + (size_t)row * EMB + col;
  else if (row < ROW_P) s = v + (size_t)(row - ROW_V) * EMB + col;
  else if (row < ROW_T) s = p + (size_t)(row - ROW_P) * EMB + col;
  else                  s = t + (size_t)(row - ROW_T) * EMB + col;
  float4 f = *(const float4*)s;
  uint2 o;
  o.x = pack_bf16x2(f.x, f.y);
  o.y = pack_bf16x2(f.z, f.w);
  *(uint2*)(feat + flat) = o;
}

// ---------- hot kernel: one 8-lane group per (relation, dst row half) ----------
// mode 0: aggregate prev -> write next (bf16), no out access.
// mode 1 (final): aggregate prev(=f2) -> f3 in regs; fused epilogue
//                 out = demb + 1/2*f1(next buf) + 1/3*f2(prev row) + 1/4*f3.
#define ACC(q) \
  a0 += __uint_as_float((q).x << 16); a1 += __uint_as_float((q).x & 0xffff0000u); \
  a2 += __uint_as_float((q).y << 16); a3 += __uint_as_float((q).y & 0xffff0000u); \
  a4 += __uint_as_float((q).z << 16); a5 += __uint_as_float((q).z & 0xffff0000u); \
  a6 += __uint_as_float((q).w << 16); a7 += __uint_as_float((q).w & 0xffff0000u);

__global__ __launch_bounds__(256) void aggr_kernel(AggrDesc d, const uint16_t* __restrict__ prev,
                                                   uint16_t* __restrict__ next,
                                                   float* __restrict__ out, int mode,
                                                   const int* __restrict__ sorted,
                                                   const int* __restrict__ Beg,
                                                   const int* __restrict__ Deg) {
  int g = blockIdx.x * 32 + (threadIdx.x >> 3);
  if (g >= TOTAL_GROUPS) return;
  int lane = threadIdx.x & 7;
  int r = 0;
#pragma unroll
  for (int k = 1; k < 8; ++k) if (g >= d.cum[k]) r = k;
  int n = g - d.cum[r];
  int beg = Beg[g], dg = Deg[g];
  float recip = 1.0f / (float)(dg > 0 ? dg : 1);
  const uint16_t* sbase = prev + (size_t)d.src_base[r] * EMB + d.src_col[r] + lane * 8;
  float a0 = 0.f, a1 = 0.f, a2 = 0.f, a3 = 0.f, a4 = 0.f, a5 = 0.f, a6 = 0.f, a7 = 0.f;
  int e = beg, end = beg + dg;
  for (; e + 4 <= end; e += 4) {
    int s0 = sorted[e], s1 = sorted[e + 1], s2 = sorted[e + 2], s3 = sorted[e + 3];
    uint4 q0 = *(const uint4*)(sbase + (size_t)s0 * EMB);
    uint4 q1 = *(const uint4*)(sbase + (size_t)s1 * EMB);
    uint4 q2 = *(const uint4*)(sbase + (size_t)s2 * EMB);
    uint4 q3 = *(const uint4*)(sbase + (size_t)s3 * EMB);
    ACC(q0); ACC(q1); ACC(q2); ACC(q3);
  }
  for (; e < end; ++e) {
    int s0 = sorted[e];
    uint4 q = *(const uint4*)(sbase + (size_t)s0 * EMB);
    ACC(q);
  }
  a0 *= recip; a1 *= recip; a2 *= recip; a3 *= recip;
  a4 *= recip; a5 *= recip; a6 *= recip; a7 *= recip;

  int col = d.dst_col[r] + lane * 8;
  size_t dpos = (size_t)(d.dst_base[r] + n) * EMB + col;

  if (mode == 0) {
    uint4 ov;
    ov.x = pack_bf16x2(a0, a1);
    ov.y = pack_bf16x2(a2, a3);
    ov.z = pack_bf16x2(a4, a5);
    ov.w = pack_bf16x2(a6, a7);
    *(uint4*)(next + dpos) = ov;
    return;
  }

  // final fused epilogue
  uint4 q1 = *(const uint4*)(next + dpos);   // f1 (bf16)
  uint4 q2 = *(const uint4*)(prev + dpos);   // f2 (bf16)
  const float* de = d.demb[r] + (size_t)n * EMB + col;
  float4 v0 = *(const float4*)de;
  float4 v1 = *((const float4*)de + 1);
  const float w1 = 0.5f, w2 = 1.0f / 3.0f, w3 = 0.25f;
  v0.x += w1 * __uint_as_float(q1.x << 16)        + w2 * __uint_as_float(q2.x << 16)        + w3 * a0;
  v0.y += w1 * __uint_as_float(q1.x & 0xffff0000u) + w2 * __uint_as_float(q2.x & 0xffff0000u) + w3 * a1;
  v0.z += w1 * __uint_as_float(q1.y << 16)        + w2 * __uint_as_float(q2.y << 16)        + w3 * a2;
  v0.w += w1 * __uint_as_float(q1.y & 0xffff0000u) + w2 * __uint_as_float(q2.y & 0xffff0000u) + w3 * a3;
  v1.x += w1 * __uint_as_float(q1.z << 16)        + w2 * __uint_as_float(q2.z << 16)        + w3 * a4;
  v1.y += w1 * __uint_as_float(q1.z & 0xffff0000u) + w2 * __uint_as_float(q2.z & 0xffff0000u) + w3 * a5;
  v1.z += w1 * __uint_as_float(q1.w << 16)        + w2 * __uint_as_float(q2.w << 16)        + w3 * a6;
  v1.w += w1 * __uint_as_float(q1.w & 0xffff0000u) + w2 * __uint_as_float(q2.w & 0xffff0000u) + w3 * a7;
  *(float4*)(out + dpos) = v0;
  *((float4*)(out + dpos) + 1) = v1;
}

// ---------- host ----------
extern "C" void kernel_launch(void* const* d_in, const int* in_sizes, int n_in,
                              void* d_out, int out_size, void* d_ws, size_t ws_size,
                              hipStream_t stream) {
  const float* emb_u = (const float*)d_in[0];
  const float* emb_v = (const float*)d_in[1];
  const float* emb_p = (const float*)d_in[2];
  const float* emb_t = (const float*)d_in[3];

  // {src_idx, dst_idx, E, n_dst, src_base, src_col, dst_base, dst_col, wshift}
  struct RelInfo { int si, di, E, n_dst, src_base, src_col, dst_base, dst_col, wshift; };
  const RelInfo rels[8] = {
    {12, 13,  800000, N_TAG,   ROW_V, 64, ROW_T,  0,  5},  // vt
    {16, 17,  400000, N_TAG,   ROW_P, 64, ROW_T, 64,  5},  // pt
    { 8,  9,  800000, N_PUB,   ROW_U, 64, ROW_P,  0,  7},  // up
    {18, 19,  400000, N_PUB,   ROW_T, 64, ROW_P, 64,  7},  // tp
    { 4,  5, 1500000, N_VIDEO, ROW_U,  0, ROW_V,  0,  9},  // uv
    {14, 15,  800000, N_VIDEO, ROW_T,  0, ROW_V, 64,  9},  // tv
    { 6,  7, 1500000, N_USER,  ROW_V,  0, ROW_U,  0, 10},  // vu
    {10, 11,  800000, N_USER,  ROW_P,  0, ROW_U, 64, 10},  // pu
  };
  const float* dembs[8] = {emb_t, emb_t, emb_p, emb_p, emb_v, emb_v, emb_u, emb_u};

  // ---- ws layout: featA | featB | sorted | Beg | Deg | cursors | bases
  // pairs (69MB, packed u32) aliases featA (83MB); dead before convert writes featA
  char* ws = (char*)d_ws;
  size_t cursor = 0;
  auto take = [&](size_t bytes) -> char* {
    char* p = ws + cursor;
    cursor = (cursor + bytes + 255) & ~(size_t)255;
    return p;
  };
  uint16_t* featA = (uint16_t*)take((size_t)ROWS * EMB * 2);
  uint16_t* featB = (uint16_t*)take((size_t)ROWS * EMB * 2);
  int* sorted = (int*)take((size_t)TOTAL_E * 4);
  int* Beg    = (int*)take((size_t)TOTAL_GROUPS * 4);
  int* Deg    = (int*)take((size_t)TOTAL_GROUPS * 4);
  unsigned* pairs = (unsigned*)d_ws;   // alias over featA

  SortDesc sd;
  AggrDesc ad;
  int tacc = 0, bacc = 0, gacc = 0;
  for (int r = 0; r < 8; ++r) {
    int n_dst = rels[r].n_dst;
    sd.tcum[r] = tacc; tacc += (rels[r].E + TILE - 1) / TILE;
    sd.bcum[r] = bacc; bacc += (n_dst + (1 << rels[r].wshift) - 1) >> rels[r].wshift;
    sd.gcum[r] = gacc;
    sd.E[r] = rels[r].E;
    sd.n_dst[r] = n_dst;
    sd.wshift[r] = rels[r].wshift;
    sd.esrc[r] = (const int*)d_in[rels[r].si];
    sd.edst[r] = (const int*)d_in[rels[r].di];

    ad.cum[r] = gacc;
    ad.src_base[r] = rels[r].src_base;
    ad.src_col[r] = rels[r].src_col;
    ad.dst_base[r] = rels[r].dst_base;
    ad.dst_col[r] = rels[r].dst_col;
    ad.demb[r] = dembs[r];
    gacc += n_dst;
  }
  sd.tcum[8] = tacc;
  sd.bcum[8] = bacc;
  ad.cum[8] = gacc;    // 650000

  int* cursors = (int*)take((size_t)bacc * 4);
  int* bases   = (int*)take((size_t)bacc * 4);

  // ---- CSR build
  hipMemsetAsync(cursors, 0, (size_t)bacc * 4, stream);
  part_kernel<<<tacc, 256, 0, stream>>>(sd, pairs, cursors);
  bases_kernel<<<1, 256, 0, stream>>>(cursors, bases, bacc);
  build_kernel<<<bacc, 256, 0, stream>>>(sd, pairs, cursors, bases, sorted, Beg, Deg);

  // ---- bf16 feature init (after pairs region is dead)
  convert_kernel<<<(ROWS * EMB / 4 + 255) / 256, 256, 0, stream>>>(emb_u, emb_v, emb_p, emb_t, featA);

  // ---- 3 layers: featA -> featB (f1), featB -> featA (f2), final fused
  float* out = (float*)d_out;
  const int aggr_blocks = (TOTAL_GROUPS + 31) / 32;
  // layer 0: prev=featA(input), next=featB  -> featB = f1
  aggr_kernel<<<aggr_blocks, 256, 0, stream>>>(ad, featA, featB, out, 0, sorted, Beg, Deg);
  // layer 1: prev=featB(f1), next=featA     -> featA = f2   (featB keeps f1)
  aggr_kernel<<<aggr_blocks, 256, 0, stream>>>(ad, featB, featA, out, 0, sorted, Beg, Deg);
  // layer 2 final: prev=featA(f2), next=featB(f1, read-only) -> out fused
  aggr_kernel<<<aggr_blocks, 256, 0, stream>>>(ad, featA, featB, out, 1, sorted, Beg, Deg);
}

// Round 4
// 618.830 us; speedup vs baseline: 3.7326x; 1.0335x over previous
//
#include <hip/hip_runtime.h>
#include <hip/hip_bf16.h>
#include <stdint.h>

#define EMB 128
#define CAP 12288          // max edges per bucket (avg <=7700, huge margin)

static constexpr int N_USER = 200000, N_VIDEO = 100000, N_PUB = 20000, N_TAG = 5000;
static constexpr int ROW_U = 0, ROW_V = 200000, ROW_P = 300000, ROW_T = 320000;
static constexpr int ROWS = 325000;
static constexpr int TOTAL_E = 7000000;
static constexpr int TOTAL_GROUPS = 650000;
static constexpr int TILE = 8192;

// ---------- bf16 helpers ----------
__device__ inline unsigned bf16_rne(float f) {
  unsigned u = __float_as_uint(f);
  return (u + 0x7fffu + ((u >> 16) & 1u)) >> 16;
}
__device__ inline unsigned pack_bf16x2(float lo, float hi) {
  return bf16_rne(lo) | (bf16_rne(hi) << 16);
}

// ---------- descriptors ----------
struct SortDesc {
  int tcum[9];            // tile prefix per relation
  int bcum[9];            // bucket prefix per relation
  int gcum[8];            // group (dst row) prefix per relation
  int E[8];
  int n_dst[8];
  int wshift[8];          // log2(dsts per bucket)
  const int* esrc[8];
  const int* edst[8];
};

struct AggrDesc {
  int cum[9];
  int src_base[8];
  int src_col[8];
  int dst_base[8];
  int dst_col[8];
  const float* demb[8];   // f32 input emb of dst node type (final epilogue)
};

// ---------- pass 1: bin edges into dst-range buckets (packed 4B pairs) ----------
__global__ __launch_bounds__(256) void part_kernel(SortDesc d, unsigned* __restrict__ pairs,
                                                   int* __restrict__ cursors) {
  __shared__ int cnt[256];
  __shared__ int lcur[256];
  int blk = blockIdx.x;
  int r = 0;
#pragma unroll
  for (int k = 1; k < 8; ++k) if (blk >= d.tcum[k]) r = k;
  int base = (blk - d.tcum[r]) * TILE;
  int n = min(TILE, d.E[r] - base);
  const int* __restrict__ esrc = d.esrc[r];
  const int* __restrict__ edst = d.edst[r];
  int tid = threadIdx.x;
  int B = d.bcum[r + 1] - d.bcum[r];
  int sh = d.wshift[r];
  int msk = (1 << sh) - 1;
  int bb = d.bcum[r];
  if (tid < B) cnt[tid] = 0;
  __syncthreads();
  for (int i = tid; i < n; i += 256)
    atomicAdd(&cnt[edst[base + i] >> sh], 1);
  __syncthreads();
  if (tid < B) {
    int c = cnt[tid];
    lcur[tid] = c ? atomicAdd(&cursors[bb + tid], c) : 0;
  }
  __syncthreads();
  for (int i = tid; i < n; i += 256) {
    int dv = edst[base + i];
    int sv = esrc[base + i];
    int b = dv >> sh;
    int pos = atomicAdd(&lcur[b], 1);
    if (pos < CAP)
      pairs[(size_t)(bb + b) * CAP + pos] = ((unsigned)(dv & msk) << 18) | (unsigned)sv;
  }
}

// ---------- exclusive scan over bucket counts -> bucket bases ----------
__global__ __launch_bounds__(256) void bases_kernel(const int* __restrict__ cursors,
                                                    int* __restrict__ bases, int NB) {
  __shared__ int wsums[4];
  int tid = threadIdx.x;
  int L = (NB + 255) / 256;
  int lo = min(tid * L, NB), hi = min(lo + L, NB);
  int s = 0;
  for (int i = lo; i < hi; ++i) s += cursors[i];
  int lane = tid & 63, wv = tid >> 6;
  int v = s;
#pragma unroll
  for (int dd = 1; dd < 64; dd <<= 1) {
    int t = __shfl_up(v, dd);
    if (lane >= dd) v += t;
  }
  if (lane == 63) wsums[wv] = v;
  __syncthreads();
  if (tid == 0) {
    int run = 0;
#pragma unroll
    for (int k = 0; k < 4; ++k) { int t = wsums[k]; wsums[k] = run; run += t; }
  }
  __syncthreads();
  int run = wsums[wv] + (v - s);
  for (int i = lo; i < hi; ++i) { int c = cursors[i]; bases[i] = run; run += c; }
}

// ---------- pass 2: per-bucket counting sort in LDS, coalesced writeout ----------
__global__ __launch_bounds__(256) void build_kernel(SortDesc d, const unsigned* __restrict__ pairs,
                                                    const int* __restrict__ cursors,
                                                    const int* __restrict__ bases,
                                                    int* __restrict__ sorted,
                                                    int* __restrict__ Beg, int* __restrict__ Deg) {
  __shared__ int cnt[1024];
  __shared__ int stage[CAP];
  __shared__ int wsums[4];
  int bucket = blockIdx.x;
  int r = 0;
#pragma unroll
  for (int k = 1; k < 8; ++k) if (bucket >= d.bcum[k]) r = k;
  int bl = bucket - d.bcum[r];
  int sh = d.wshift[r];
  int first = bl << sh;
  int Wa = min(1 << sh, d.n_dst[r] - first);
  int tid = threadIdx.x;
  int n_b = min(cursors[bucket], CAP);
  int gbase = bases[bucket];
  const unsigned* __restrict__ bp = pairs + (size_t)bucket * CAP;

  for (int i = tid; i < 1024; i += 256) cnt[i] = 0;
  __syncthreads();
  for (int i = tid; i < n_b; i += 256)
    atomicAdd(&cnt[bp[i] >> 18], 1);
  __syncthreads();

  // block exclusive scan of cnt[0..1024), 4 per thread
  int t4 = tid * 4;
  int c0 = cnt[t4], c1 = cnt[t4 + 1], c2 = cnt[t4 + 2], c3 = cnt[t4 + 3];
  int s = c0 + c1 + c2 + c3;
  int lane = tid & 63, wv = tid >> 6;
  int v = s;
#pragma unroll
  for (int dd = 1; dd < 64; dd <<= 1) {
    int t = __shfl_up(v, dd);
    if (lane >= dd) v += t;
  }
  if (lane == 63) wsums[wv] = v;
  __syncthreads();
  if (tid == 0) {
    int run = 0;
#pragma unroll
    for (int k = 0; k < 4; ++k) { int t = wsums[k]; wsums[k] = run; run += t; }
  }
  __syncthreads();
  int ex = wsums[wv] + (v - s);
  int o0 = ex, o1 = ex + c0, o2 = o1 + c1, o3 = o2 + c2;
  cnt[t4] = o0; cnt[t4 + 1] = o1; cnt[t4 + 2] = o2; cnt[t4 + 3] = o3;
  int g0 = d.gcum[r] + first + t4;
  if (t4 + 0 < Wa) { Beg[g0 + 0] = gbase + o0; Deg[g0 + 0] = c0; }
  if (t4 + 1 < Wa) { Beg[g0 + 1] = gbase + o1; Deg[g0 + 1] = c1; }
  if (t4 + 2 < Wa) { Beg[g0 + 2] = gbase + o2; Deg[g0 + 2] = c2; }
  if (t4 + 3 < Wa) { Beg[g0 + 3] = gbase + o3; Deg[g0 + 3] = c3; }
  __syncthreads();

  for (int i = tid; i < n_b; i += 256) {
    unsigned pr = bp[i];
    int pos = atomicAdd(&cnt[pr >> 18], 1);
    stage[pos] = (int)(pr & 0x3FFFFu);
  }
  __syncthreads();
  for (int i = tid; i < n_b; i += 256)
    sorted[gbase + i] = stage[i];
}

// ---------- f32 inputs -> bf16 feature buffer (32B in / 16B out per thread) ----------
__global__ void convert_kernel(const float* __restrict__ u, const float* __restrict__ v,
                               const float* __restrict__ p, const float* __restrict__ t,
                               uint16_t* __restrict__ feat) {
  int idx = blockIdx.x * blockDim.x + threadIdx.x;
  const int total8 = ROWS * EMB / 8;
  if (idx >= total8) return;
  int flat = idx * 8;
  int row = flat >> 7;
  int col = flat & 127;
  const float* s;
  if (row < ROW_V)      s = u + (size_t)row * EMB + col;
  else if (row < ROW_P) s = v + (size_t)(row - ROW_V) * EMB + col;
  else if (row < ROW_T) s = p + (size_t)(row - ROW_P) * EMB + col;
  else                  s = t + (size_t)(row - ROW_T) * EMB + col;
  float4 f0 = *(const float4*)s;
  float4 f1 = *((const float4*)s + 1);
  uint4 o;
  o.x = pack_bf16x2(f0.x, f0.y);
  o.y = pack_bf16x2(f0.z, f0.w);
  o.z = pack_bf16x2(f1.x, f1.y);
  o.w = pack_bf16x2(f1.z, f1.w);
  *(uint4*)(feat + flat) = o;
}

// ---------- hot kernel: one 8-lane group per (relation, dst row half) ----------
// Chunk-of-8 gather: lane l loads sorted[e+l] (1 coalesced VMEM), indices
// broadcast via __shfl(.,j,8), 8 independent dwordx4 gathers in flight.
#define ACC(q) \
  a0 += __uint_as_float((q).x << 16); a1 += __uint_as_float((q).x & 0xffff0000u); \
  a2 += __uint_as_float((q).y << 16); a3 += __uint_as_float((q).y & 0xffff0000u); \
  a4 += __uint_as_float((q).z << 16); a5 += __uint_as_float((q).z & 0xffff0000u); \
  a6 += __uint_as_float((q).w << 16); a7 += __uint_as_float((q).w & 0xffff0000u);

__global__ __launch_bounds__(256) void aggr_kernel(AggrDesc d, const uint16_t* __restrict__ prev,
                                                   uint16_t* __restrict__ next,
                                                   float* __restrict__ out, int mode,
                                                   const int* __restrict__ sorted,
                                                   const int* __restrict__ Beg,
                                                   const int* __restrict__ Deg) {
  int g = blockIdx.x * 32 + (threadIdx.x >> 3);
  if (g >= TOTAL_GROUPS) return;
  int lane = threadIdx.x & 7;
  int r = 0;
#pragma unroll
  for (int k = 1; k < 8; ++k) if (g >= d.cum[k]) r = k;
  int n = g - d.cum[r];
  int beg = Beg[g], dg = Deg[g];
  float recip = 1.0f / (float)(dg > 0 ? dg : 1);
  const uint16_t* sbase = prev + (size_t)d.src_base[r] * EMB + d.src_col[r] + lane * 8;
  float a0 = 0.f, a1 = 0.f, a2 = 0.f, a3 = 0.f, a4 = 0.f, a5 = 0.f, a6 = 0.f, a7 = 0.f;
  int e = beg, end = beg + dg;
  // full chunks of 8
  while (e + 8 <= end) {
    int myi = sorted[e + lane];
    uint4 q[8];
#pragma unroll
    for (int j = 0; j < 8; ++j) {
      int sj = __shfl(myi, j, 8);
      q[j] = *(const uint4*)(sbase + (size_t)sj * EMB);
    }
#pragma unroll
    for (int j = 0; j < 8; ++j) { ACC(q[j]); }
    e += 8;
  }
  // guarded tail chunk (rem in 1..7), loads stay independent
  int rem = end - e;
  if (rem > 0) {
    int myi = sorted[e + (lane < rem ? lane : 0)];
    uint4 q[7];
#pragma unroll
    for (int j = 0; j < 7; ++j) {
      if (j < rem) {
        int sj = __shfl(myi, j, 8);
        q[j] = *(const uint4*)(sbase + (size_t)sj * EMB);
      }
    }
#pragma unroll
    for (int j = 0; j < 7; ++j) {
      if (j < rem) { ACC(q[j]); }
    }
  }
  a0 *= recip; a1 *= recip; a2 *= recip; a3 *= recip;
  a4 *= recip; a5 *= recip; a6 *= recip; a7 *= recip;

  int col = d.dst_col[r] + lane * 8;
  size_t dpos = (size_t)(d.dst_base[r] + n) * EMB + col;

  if (mode == 0) {
    uint4 ov;
    ov.x = pack_bf16x2(a0, a1);
    ov.y = pack_bf16x2(a2, a3);
    ov.z = pack_bf16x2(a4, a5);
    ov.w = pack_bf16x2(a6, a7);
    *(uint4*)(next + dpos) = ov;
    return;
  }

  // final fused epilogue: out = demb + 1/2*f1 + 1/3*f2 + 1/4*f3
  uint4 q1 = *(const uint4*)(next + dpos);   // f1 (bf16)
  uint4 q2 = *(const uint4*)(prev + dpos);   // f2 (bf16)
  const float* de = d.demb[r] + (size_t)n * EMB + col;
  float4 v0 = *(const float4*)de;
  float4 v1 = *((const float4*)de + 1);
  const float w1 = 0.5f, w2 = 1.0f / 3.0f, w3 = 0.25f;
  v0.x += w1 * __uint_as_float(q1.x << 16)         + w2 * __uint_as_float(q2.x << 16)         + w3 * a0;
  v0.y += w1 * __uint_as_float(q1.x & 0xffff0000u) + w2 * __uint_as_float(q2.x & 0xffff0000u) + w3 * a1;
  v0.z += w1 * __uint_as_float(q1.y << 16)         + w2 * __uint_as_float(q2.y << 16)         + w3 * a2;
  v0.w += w1 * __uint_as_float(q1.y & 0xffff0000u) + w2 * __uint_as_float(q2.y & 0xffff0000u) + w3 * a3;
  v1.x += w1 * __uint_as_float(q1.z << 16)         + w2 * __uint_as_float(q2.z << 16)         + w3 * a4;
  v1.y += w1 * __uint_as_float(q1.z & 0xffff0000u) + w2 * __uint_as_float(q2.z & 0xffff0000u) + w3 * a5;
  v1.z += w1 * __uint_as_float(q1.w << 16)         + w2 * __uint_as_float(q2.w << 16)         + w3 * a6;
  v1.w += w1 * __uint_as_float(q1.w & 0xffff0000u) + w2 * __uint_as_float(q2.w & 0xffff0000u) + w3 * a7;
  *(float4*)(out + dpos) = v0;
  *((float4*)(out + dpos) + 1) = v1;
}

// ---------- host ----------
extern "C" void kernel_launch(void* const* d_in, const int* in_sizes, int n_in,
                              void* d_out, int out_size, void* d_ws, size_t ws_size,
                              hipStream_t stream) {
  const float* emb_u = (const float*)d_in[0];
  const float* emb_v = (const float*)d_in[1];
  const float* emb_p = (const float*)d_in[2];
  const float* emb_t = (const float*)d_in[3];

  // {src_idx, dst_idx, E, n_dst, src_base, src_col, dst_base, dst_col, wshift}
  struct RelInfo { int si, di, E, n_dst, src_base, src_col, dst_base, dst_col, wshift; };
  const RelInfo rels[8] = {
    {12, 13,  800000, N_TAG,   ROW_V, 64, ROW_T,  0,  5},  // vt
    {16, 17,  400000, N_TAG,   ROW_P, 64, ROW_T, 64,  5},  // pt
    { 8,  9,  800000, N_PUB,   ROW_U, 64, ROW_P,  0,  7},  // up
    {18, 19,  400000, N_PUB,   ROW_T, 64, ROW_P, 64,  7},  // tp
    { 4,  5, 1500000, N_VIDEO, ROW_U,  0, ROW_V,  0,  9},  // uv
    {14, 15,  800000, N_VIDEO, ROW_T,  0, ROW_V, 64,  9},  // tv
    { 6,  7, 1500000, N_USER,  ROW_V,  0, ROW_U,  0, 10},  // vu
    {10, 11,  800000, N_USER,  ROW_P,  0, ROW_U, 64, 10},  // pu
  };
  const float* dembs[8] = {emb_t, emb_t, emb_p, emb_p, emb_v, emb_v, emb_u, emb_u};

  // ---- ws layout: featA | featB | sorted | Beg | Deg | cursors | bases
  // pairs (69MB, packed u32) aliases featA (83MB); dead before convert writes featA
  char* ws = (char*)d_ws;
  size_t cursor = 0;
  auto take = [&](size_t bytes) -> char* {
    char* p = ws + cursor;
    cursor = (cursor + bytes + 255) & ~(size_t)255;
    return p;
  };
  uint16_t* featA = (uint16_t*)take((size_t)ROWS * EMB * 2);
  uint16_t* featB = (uint16_t*)take((size_t)ROWS * EMB * 2);
  int* sorted = (int*)take((size_t)TOTAL_E * 4);
  int* Beg    = (int*)take((size_t)TOTAL_GROUPS * 4);
  int* Deg    = (int*)take((size_t)TOTAL_GROUPS * 4);
  unsigned* pairs = (unsigned*)d_ws;   // alias over featA

  SortDesc sd;
  AggrDesc ad;
  int tacc = 0, bacc = 0, gacc = 0;
  for (int r = 0; r < 8; ++r) {
    int n_dst = rels[r].n_dst;
    sd.tcum[r] = tacc; tacc += (rels[r].E + TILE - 1) / TILE;
    sd.bcum[r] = bacc; bacc += (n_dst + (1 << rels[r].wshift) - 1) >> rels[r].wshift;
    sd.gcum[r] = gacc;
    sd.E[r] = rels[r].E;
    sd.n_dst[r] = n_dst;
    sd.wshift[r] = rels[r].wshift;
    sd.esrc[r] = (const int*)d_in[rels[r].si];
    sd.edst[r] = (const int*)d_in[rels[r].di];

    ad.cum[r] = gacc;
    ad.src_base[r] = rels[r].src_base;
    ad.src_col[r] = rels[r].src_col;
    ad.dst_base[r] = rels[r].dst_base;
    ad.dst_col[r] = rels[r].dst_col;
    ad.demb[r] = dembs[r];
    gacc += n_dst;
  }
  sd.tcum[8] = tacc;
  sd.bcum[8] = bacc;
  ad.cum[8] = gacc;    // 650000

  int* cursors = (int*)take((size_t)bacc * 4);
  int* bases   = (int*)take((size_t)bacc * 4);

  // ---- CSR build
  hipMemsetAsync(cursors, 0, (size_t)bacc * 4, stream);
  part_kernel<<<tacc, 256, 0, stream>>>(sd, pairs, cursors);
  bases_kernel<<<1, 256, 0, stream>>>(cursors, bases, bacc);
  build_kernel<<<bacc, 256, 0, stream>>>(sd, pairs, cursors, bases, sorted, Beg, Deg);

  // ---- bf16 feature init (after pairs region is dead)
  convert_kernel<<<(ROWS * EMB / 8 + 255) / 256, 256, 0, stream>>>(emb_u, emb_v, emb_p, emb_t, featA);

  // ---- 3 layers: featA -> featB (f1), featB -> featA (f2), final fused
  float* out = (float*)d_out;
  const int aggr_blocks = (TOTAL_GROUPS + 31) / 32;
  // layer 0: prev=featA(input), next=featB  -> featB = f1
  aggr_kernel<<<aggr_blocks, 256, 0, stream>>>(ad, featA, featB, out, 0, sorted, Beg, Deg);
  // layer 1: prev=featB(f1), next=featA     -> featA = f2   (featB keeps f1)
  aggr_kernel<<<aggr_blocks, 256, 0, stream>>>(ad, featB, featA, out, 0, sorted, Beg, Deg);
  // layer 2 final: prev=featA(f2), next=featB(f1, read-only) -> out fused
  aggr_kernel<<<aggr_blocks, 256, 0, stream>>>(ad, featA, featB, out, 1, sorted, Beg, Deg);
}

// Round 5
// 617.498 us; speedup vs baseline: 3.7407x; 1.0022x over previous
//
#include <hip/hip_runtime.h>
#include <stdint.h>

#define EMB 128
#define PCAP 12288          // pairs stride per bucket (real edges; avg <=7700)
#define SCAP 13312          // stage capacity (padded edges per bucket)

static constexpr int N_USER = 200000, N_VIDEO = 100000, N_PUB = 20000, N_TAG = 5000;
static constexpr int ROW_U = 0, ROW_V = 200000, ROW_P = 300000, ROW_T = 320000;
static constexpr int ROWS = 325000;           // + 1 extra zero row at index ROWS
static constexpr int TOTAL_E = 7000000;
static constexpr int TOTAL_GROUPS = 650000;
static constexpr int TILE = 8192;
static constexpr int SORT_MAX = TOTAL_E + 7 * TOTAL_GROUPS;  // hard bound on padded edges

using f32x4 = __attribute__((ext_vector_type(4))) float;
using u32x4 = __attribute__((ext_vector_type(4))) unsigned int;

// ---------- bf16 helpers ----------
__device__ inline unsigned bf16_rne(float f) {
  unsigned u = __float_as_uint(f);
  return (u + 0x7fffu + ((u >> 16) & 1u)) >> 16;
}
__device__ inline unsigned pack_bf16x2(float lo, float hi) {
  return bf16_rne(lo) | (bf16_rne(hi) << 16);
}

// ---------- descriptors ----------
struct SortDesc {
  int tcum[9];            // tile prefix per relation
  int bcum[9];            // bucket prefix per relation
  int gcum[8];            // group (dst row) prefix per relation
  int E[8];
  int n_dst[8];
  int wshift[8];          // log2(dsts per bucket)
  int zrow[8];            // ROWS - src_base[r]: local sentinel -> global zero row
  const int* esrc[8];
  const int* edst[8];
};

struct AggrDesc {
  int cum[9];
  int src_base[8];
  int src_col[8];
  int dst_base[8];
  int dst_col[8];
  const float* demb[8];   // f32 input emb of dst node type (final epilogue)
};

// ---------- pass 1: bin edges into dst-range buckets (packed 4B pairs) ----------
__global__ __launch_bounds__(256) void part_kernel(SortDesc d, unsigned* __restrict__ pairs,
                                                   int* __restrict__ cursors) {
  __shared__ int cnt[256];
  __shared__ int lcur[256];
  int blk = blockIdx.x;
  int r = 0;
#pragma unroll
  for (int k = 1; k < 8; ++k) if (blk >= d.tcum[k]) r = k;
  int base = (blk - d.tcum[r]) * TILE;
  int n = min(TILE, d.E[r] - base);
  const int* __restrict__ esrc = d.esrc[r];
  const int* __restrict__ edst = d.edst[r];
  int tid = threadIdx.x;
  int B = d.bcum[r + 1] - d.bcum[r];
  int sh = d.wshift[r];
  int msk = (1 << sh) - 1;
  int bb = d.bcum[r];
  if (tid < B) cnt[tid] = 0;
  __syncthreads();
  for (int i = tid; i < n; i += 256)
    atomicAdd(&cnt[edst[base + i] >> sh], 1);
  __syncthreads();
  if (tid < B) {
    int c = cnt[tid];
    lcur[tid] = c ? atomicAdd(&cursors[bb + tid], c) : 0;
  }
  __syncthreads();
  for (int i = tid; i < n; i += 256) {
    int dv = edst[base + i];
    int sv = esrc[base + i];
    int b = dv >> sh;
    int pos = atomicAdd(&lcur[b], 1);
    if (pos < PCAP)
      pairs[(size_t)(bb + b) * PCAP + pos] = ((unsigned)(dv & msk) << 18) | (unsigned)sv;
  }
}

// ---------- pass 2: per-bucket counting sort in LDS with 8-padding ----------
// Per-dst edge lists padded to multiple of 8 with the zero-row sentinel so the
// aggregation loop is branchless full chunks. Block atomically reserves its
// padded span in `sorted` (layout nondeterministic; output values unaffected).
__global__ __launch_bounds__(256) void build_kernel(SortDesc d, const unsigned* __restrict__ pairs,
                                                    const int* __restrict__ cursors,
                                                    int* __restrict__ gcounter,
                                                    int* __restrict__ sorted,
                                                    int* __restrict__ Beg, int* __restrict__ Deg) {
  __shared__ int cnt[1024];     // counts -> scatter cursors
  __shared__ int poff[1025];    // padded exclusive offsets (+ total)
  __shared__ int stage[SCAP];
  __shared__ int wsums[4];
  __shared__ int sh_gbase;
  int bucket = blockIdx.x;
  int r = 0;
#pragma unroll
  for (int k = 1; k < 8; ++k) if (bucket >= d.bcum[k]) r = k;
  int bl = bucket - d.bcum[r];
  int sh = d.wshift[r];
  int first = bl << sh;
  int Wa = min(1 << sh, d.n_dst[r] - first);
  int zr = d.zrow[r];
  int tid = threadIdx.x;
  int n_b = min(cursors[bucket], PCAP);
  const unsigned* __restrict__ bp = pairs + (size_t)bucket * PCAP;

  for (int i = tid; i < 1024; i += 256) cnt[i] = 0;
  __syncthreads();
  for (int i = tid; i < n_b; i += 256)
    atomicAdd(&cnt[bp[i] >> 18], 1);
  __syncthreads();

  // padded exclusive scan of cnt[0..1024), 4 per thread
  int t4 = tid * 4;
  int c0 = cnt[t4], c1 = cnt[t4 + 1], c2 = cnt[t4 + 2], c3 = cnt[t4 + 3];
  int p0 = (c0 + 7) & ~7, p1 = (c1 + 7) & ~7, p2 = (c2 + 7) & ~7, p3 = (c3 + 7) & ~7;
  int s = p0 + p1 + p2 + p3;
  int lane = tid & 63, wv = tid >> 6;
  int v = s;
#pragma unroll
  for (int dd = 1; dd < 64; dd <<= 1) {
    int t = __shfl_up(v, dd);
    if (lane >= dd) v += t;
  }
  if (lane == 63) wsums[wv] = v;
  __syncthreads();
  if (tid == 0) {
    int run = 0;
#pragma unroll
    for (int k = 0; k < 4; ++k) { int t = wsums[k]; wsums[k] = run; run += t; }
  }
  __syncthreads();
  int ex = wsums[wv] + (v - s);
  if (tid == 255) {
    int tot = ex + s;                       // padded bucket total
    sh_gbase = atomicAdd(gcounter, tot);    // reserve span in sorted
    poff[1024] = min(tot, SCAP);
  }
  __syncthreads();
  int gbase = sh_gbase;
  int o0 = ex, o1 = ex + p0, o2 = o1 + p1, o3 = o2 + p2;
  cnt[t4] = o0; cnt[t4 + 1] = o1; cnt[t4 + 2] = o2; cnt[t4 + 3] = o3;
  poff[t4] = o0; poff[t4 + 1] = o1; poff[t4 + 2] = o2; poff[t4 + 3] = o3;
  int g0 = d.gcum[r] + first + t4;
  if (t4 + 0 < Wa) { Beg[g0 + 0] = gbase + o0; Deg[g0 + 0] = c0; }
  if (t4 + 1 < Wa) { Beg[g0 + 1] = gbase + o1; Deg[g0 + 1] = c1; }
  if (t4 + 2 < Wa) { Beg[g0 + 2] = gbase + o2; Deg[g0 + 2] = c2; }
  if (t4 + 3 < Wa) { Beg[g0 + 3] = gbase + o3; Deg[g0 + 3] = c3; }
  __syncthreads();

  // counting-sort scatter into stage
  for (int i = tid; i < n_b; i += 256) {
    unsigned pr = bp[i];
    int pos = atomicAdd(&cnt[pr >> 18], 1);
    if (pos < SCAP) stage[pos] = (int)(pr & 0x3FFFFu);
  }
  __syncthreads();

  // pad fill: [off_j + c_j, off_j + cpad_j) = zero-row sentinel
#pragma unroll
  for (int jj = 0; jj < 4; ++jj) {
    int j = t4 + jj;
    int end_ = min((j < 1023) ? poff[j + 1] : poff[1024], SCAP);
    for (int k = cnt[j]; k < end_; ++k) stage[k] = zr;
  }
  __syncthreads();

  int tot = poff[1024];
  for (int i = tid; i < tot; i += 256)
    sorted[gbase + i] = stage[i];
}

// ---------- f32 inputs -> bf16 feature buffer + zero row in both buffers ----------
__global__ void convert_kernel(const float* __restrict__ u, const float* __restrict__ v,
                               const float* __restrict__ p, const float* __restrict__ t,
                               uint16_t* __restrict__ featA, uint16_t* __restrict__ featB) {
  int idx = blockIdx.x * blockDim.x + threadIdx.x;
  const int total8 = (ROWS + 1) * EMB / 8;
  if (idx >= total8) return;
  int flat = idx * 8;
  int row = flat >> 7;
  if (row == ROWS) {
    uint4 z = {0u, 0u, 0u, 0u};
    *(uint4*)(featA + flat) = z;
    *(uint4*)(featB + flat) = z;
    return;
  }
  int col = flat & 127;
  const float* s;
  if (row < ROW_V)      s = u + (size_t)row * EMB + col;
  else if (row < ROW_P) s = v + (size_t)(row - ROW_V) * EMB + col;
  else if (row < ROW_T) s = p + (size_t)(row - ROW_P) * EMB + col;
  else                  s = t + (size_t)(row - ROW_T) * EMB + col;
  float4 f0 = *(const float4*)s;
  float4 f1 = *((const float4*)s + 1);
  uint4 o;
  o.x = pack_bf16x2(f0.x, f0.y);
  o.y = pack_bf16x2(f0.z, f0.w);
  o.z = pack_bf16x2(f1.x, f1.y);
  o.w = pack_bf16x2(f1.z, f1.w);
  *(uint4*)(featA + flat) = o;
}

// ---------- hot kernel: one 8-lane group per (relation, dst row half) ----------
// Branchless padded chunks of 8; named q0..q7 + sched_barrier force 8 gathers
// in flight; next chunk's index load issued before the ACC block.
#define ACC(q) \
  a0 += __uint_as_float((q).x << 16); a1 += __uint_as_float((q).x & 0xffff0000u); \
  a2 += __uint_as_float((q).y << 16); a3 += __uint_as_float((q).y & 0xffff0000u); \
  a4 += __uint_as_float((q).z << 16); a5 += __uint_as_float((q).z & 0xffff0000u); \
  a6 += __uint_as_float((q).w << 16); a7 += __uint_as_float((q).w & 0xffff0000u);

__global__ __launch_bounds__(256) void aggr_kernel(AggrDesc d, const uint16_t* __restrict__ prev,
                                                   uint16_t* __restrict__ next,
                                                   float* __restrict__ out, int mode,
                                                   const int* __restrict__ sorted,
                                                   const int* __restrict__ Beg,
                                                   const int* __restrict__ Deg) {
  int g = blockIdx.x * 32 + (threadIdx.x >> 3);
  if (g >= TOTAL_GROUPS) return;
  int lane = threadIdx.x & 7;
  int r = 0;
#pragma unroll
  for (int k = 1; k < 8; ++k) if (g >= d.cum[k]) r = k;
  int n = g - d.cum[r];
  int beg = Beg[g], dg = Deg[g];
  float recip = 1.0f / (float)(dg > 0 ? dg : 1);
  const uint16_t* __restrict__ sbase = prev + (size_t)d.src_base[r] * EMB + d.src_col[r] + lane * 8;
  float a0 = 0.f, a1 = 0.f, a2 = 0.f, a3 = 0.f, a4 = 0.f, a5 = 0.f, a6 = 0.f, a7 = 0.f;
  int nchunk = (dg + 7) >> 3;
  int e = beg + lane;
  int myi = (nchunk > 0) ? sorted[e] : 0;
  for (int c = 0; c < nchunk; ++c) {
    int nyi = (c + 1 < nchunk) ? sorted[e + 8] : 0;   // prefetch next chunk's indices
    int s0 = __shfl(myi, 0, 8), s1 = __shfl(myi, 1, 8);
    int s2 = __shfl(myi, 2, 8), s3 = __shfl(myi, 3, 8);
    int s4 = __shfl(myi, 4, 8), s5 = __shfl(myi, 5, 8);
    int s6 = __shfl(myi, 6, 8), s7 = __shfl(myi, 7, 8);
    uint4 q0 = *(const uint4*)(sbase + (size_t)s0 * EMB);
    uint4 q1 = *(const uint4*)(sbase + (size_t)s1 * EMB);
    uint4 q2 = *(const uint4*)(sbase + (size_t)s2 * EMB);
    uint4 q3 = *(const uint4*)(sbase + (size_t)s3 * EMB);
    uint4 q4 = *(const uint4*)(sbase + (size_t)s4 * EMB);
    uint4 q5 = *(const uint4*)(sbase + (size_t)s5 * EMB);
    uint4 q6 = *(const uint4*)(sbase + (size_t)s6 * EMB);
    uint4 q7 = *(const uint4*)(sbase + (size_t)s7 * EMB);
    __builtin_amdgcn_sched_barrier(0);   // keep all 8 gathers issued before ACCs
    ACC(q0); ACC(q1); ACC(q2); ACC(q3);
    ACC(q4); ACC(q5); ACC(q6); ACC(q7);
    myi = nyi; e += 8;
  }
  a0 *= recip; a1 *= recip; a2 *= recip; a3 *= recip;
  a4 *= recip; a5 *= recip; a6 *= recip; a7 *= recip;

  int col = d.dst_col[r] + lane * 8;
  size_t dpos = (size_t)(d.dst_base[r] + n) * EMB + col;

  if (mode == 0) {
    uint4 ov;
    ov.x = pack_bf16x2(a0, a1);
    ov.y = pack_bf16x2(a2, a3);
    ov.z = pack_bf16x2(a4, a5);
    ov.w = pack_bf16x2(a6, a7);
    *(uint4*)(next + dpos) = ov;
    return;
  }

  // final fused epilogue: out = demb + 1/2*f1 + 1/3*f2 + 1/4*f3
  // single-use streams (f1, demb, out) use nontemporal to keep LLC for gathers
  u32x4 q1 = __builtin_nontemporal_load((const u32x4*)(next + dpos));   // f1
  uint4 q2 = *(const uint4*)(prev + dpos);                              // f2 (also gather target)
  const f32x4* de = (const f32x4*)(d.demb[r] + (size_t)n * EMB + col);
  f32x4 v0 = __builtin_nontemporal_load(de);
  f32x4 v1 = __builtin_nontemporal_load(de + 1);
  const float w1 = 0.5f, w2 = 1.0f / 3.0f, w3 = 0.25f;
  v0.x += w1 * __uint_as_float(q1.x << 16)         + w2 * __uint_as_float(q2.x << 16)         + w3 * a0;
  v0.y += w1 * __uint_as_float(q1.x & 0xffff0000u) + w2 * __uint_as_float(q2.x & 0xffff0000u) + w3 * a1;
  v0.z += w1 * __uint_as_float(q1.y << 16)         + w2 * __uint_as_float(q2.y << 16)         + w3 * a2;
  v0.w += w1 * __uint_as_float(q1.y & 0xffff0000u) + w2 * __uint_as_float(q2.y & 0xffff0000u) + w3 * a3;
  v1.x += w1 * __uint_as_float(q1.z << 16)         + w2 * __uint_as_float(q2.z << 16)         + w3 * a4;
  v1.y += w1 * __uint_as_float(q1.z & 0xffff0000u) + w2 * __uint_as_float(q2.z & 0xffff0000u) + w3 * a5;
  v1.z += w1 * __uint_as_float(q1.w << 16)         + w2 * __uint_as_float(q2.w << 16)         + w3 * a6;
  v1.w += w1 * __uint_as_float(q1.w & 0xffff0000u) + w2 * __uint_as_float(q2.w & 0xffff0000u) + w3 * a7;
  __builtin_nontemporal_store(v0, (f32x4*)(out + dpos));
  __builtin_nontemporal_store(v1, (f32x4*)(out + dpos) + 1);
}

// ---------- host ----------
extern "C" void kernel_launch(void* const* d_in, const int* in_sizes, int n_in,
                              void* d_out, int out_size, void* d_ws, size_t ws_size,
                              hipStream_t stream) {
  const float* emb_u = (const float*)d_in[0];
  const float* emb_v = (const float*)d_in[1];
  const float* emb_p = (const float*)d_in[2];
  const float* emb_t = (const float*)d_in[3];

  // {src_idx, dst_idx, E, n_dst, src_base, src_col, dst_base, dst_col, wshift}
  struct RelInfo { int si, di, E, n_dst, src_base, src_col, dst_base, dst_col, wshift; };
  const RelInfo rels[8] = {
    {12, 13,  800000, N_TAG,   ROW_V, 64, ROW_T,  0,  5},  // vt
    {16, 17,  400000, N_TAG,   ROW_P, 64, ROW_T, 64,  5},  // pt
    { 8,  9,  800000, N_PUB,   ROW_U, 64, ROW_P,  0,  7},  // up
    {18, 19,  400000, N_PUB,   ROW_T, 64, ROW_P, 64,  7},  // tp
    { 4,  5, 1500000, N_VIDEO, ROW_U,  0, ROW_V,  0,  9},  // uv
    {14, 15,  800000, N_VIDEO, ROW_T,  0, ROW_V, 64,  9},  // tv
    { 6,  7, 1500000, N_USER,  ROW_V,  0, ROW_U,  0, 10},  // vu
    {10, 11,  800000, N_USER,  ROW_P,  0, ROW_U, 64, 10},  // pu
  };
  const float* dembs[8] = {emb_t, emb_t, emb_p, emb_p, emb_v, emb_v, emb_u, emb_u};

  // ---- ws layout: featA | featB | sorted | Beg | Deg | cursors | gcounter
  // pairs (69MB, packed u32) aliases featA+featB; dead before convert writes them
  char* ws = (char*)d_ws;
  size_t cursor = 0;
  auto take = [&](size_t bytes) -> char* {
    char* p = ws + cursor;
    cursor = (cursor + bytes + 255) & ~(size_t)255;
    return p;
  };
  uint16_t* featA = (uint16_t*)take((size_t)(ROWS + 1) * EMB * 2);
  uint16_t* featB = (uint16_t*)take((size_t)(ROWS + 1) * EMB * 2);
  int* sorted = (int*)take((size_t)SORT_MAX * 4);
  int* Beg    = (int*)take((size_t)TOTAL_GROUPS * 4);
  int* Deg    = (int*)take((size_t)TOTAL_GROUPS * 4);
  unsigned* pairs = (unsigned*)d_ws;   // alias over featA/featB

  SortDesc sd;
  AggrDesc ad;
  int tacc = 0, bacc = 0, gacc = 0;
  for (int r = 0; r < 8; ++r) {
    int n_dst = rels[r].n_dst;
    sd.tcum[r] = tacc; tacc += (rels[r].E + TILE - 1) / TILE;
    sd.bcum[r] = bacc; bacc += (n_dst + (1 << rels[r].wshift) - 1) >> rels[r].wshift;
    sd.gcum[r] = gacc;
    sd.E[r] = rels[r].E;
    sd.n_dst[r] = n_dst;
    sd.wshift[r] = rels[r].wshift;
    sd.zrow[r] = ROWS - rels[r].src_base;
    sd.esrc[r] = (const int*)d_in[rels[r].si];
    sd.edst[r] = (const int*)d_in[rels[r].di];

    ad.cum[r] = gacc;
    ad.src_base[r] = rels[r].src_base;
    ad.src_col[r] = rels[r].src_col;
    ad.dst_base[r] = rels[r].dst_base;
    ad.dst_col[r] = rels[r].dst_col;
    ad.demb[r] = dembs[r];
    gacc += n_dst;
  }
  sd.tcum[8] = tacc;
  sd.bcum[8] = bacc;   // 1412 buckets
  ad.cum[8] = gacc;    // 650000

  int* cursors  = (int*)take((size_t)bacc * 4 + 4);   // +1 int: gcounter
  int* gcounter = cursors + bacc;

  // ---- CSR build (padded)
  hipMemsetAsync(cursors, 0, (size_t)(bacc + 1) * 4, stream);
  part_kernel<<<tacc, 256, 0, stream>>>(sd, pairs, cursors);
  build_kernel<<<bacc, 256, 0, stream>>>(sd, pairs, cursors, gcounter, sorted, Beg, Deg);

  // ---- bf16 feature init (after pairs region is dead) + zero row
  convert_kernel<<<((ROWS + 1) * EMB / 8 + 255) / 256, 256, 0, stream>>>(
      emb_u, emb_v, emb_p, emb_t, featA, featB);

  // ---- 3 layers: featA -> featB (f1), featB -> featA (f2), final fused
  float* out = (float*)d_out;
  const int aggr_blocks = (TOTAL_GROUPS + 31) / 32;
  aggr_kernel<<<aggr_blocks, 256, 0, stream>>>(ad, featA, featB, out, 0, sorted, Beg, Deg);
  aggr_kernel<<<aggr_blocks, 256, 0, stream>>>(ad, featB, featA, out, 0, sorted, Beg, Deg);
  aggr_kernel<<<aggr_blocks, 256, 0, stream>>>(ad, featA, featB, out, 1, sorted, Beg, Deg);
}

// Round 6
// 606.032 us; speedup vs baseline: 3.8114x; 1.0189x over previous
//
#include <hip/hip_runtime.h>
#include <stdint.h>

#define EMB 128
#define PCAP 12288          // pairs stride per bucket (real edges; avg <=7700)
#define SCAP 13312          // stage capacity (padded edges per bucket)

static constexpr int N_USER = 200000, N_VIDEO = 100000, N_PUB = 20000, N_TAG = 5000;
static constexpr int ROW_U = 0, ROW_V = 200000, ROW_P = 300000, ROW_T = 320000;
static constexpr int ROWS = 325000;           // + 1 extra zero row at index ROWS
static constexpr int TOTAL_E = 7000000;
static constexpr int TOTAL_GROUPS = 650000;
static constexpr int TILE = 8192;
static constexpr int SORT_MAX = TOTAL_E + 7 * TOTAL_GROUPS;

using f32x4 = __attribute__((ext_vector_type(4))) float;
using u32x4 = __attribute__((ext_vector_type(4))) unsigned int;
using u32x2 = __attribute__((ext_vector_type(2))) unsigned int;

// ---------- bf16 helpers ----------
__device__ inline unsigned bf16_rne(float f) {
  unsigned u = __float_as_uint(f);
  return (u + 0x7fffu + ((u >> 16) & 1u)) >> 16;
}
__device__ inline unsigned pack_bf16x2(float lo, float hi) {
  return bf16_rne(lo) | (bf16_rne(hi) << 16);
}

// ---------- fp8 e4m3fn helpers ----------
// Encode: software RNE (HW pk-cvt rounding mode unverified on gfx950).
__device__ inline unsigned fp8enc(float f) {
  unsigned b = __float_as_uint(f);
  unsigned s = (b >> 24) & 0x80u;
  unsigned ae = b & 0x7FFFFFFFu;
  unsigned r = ae + 0x7FFFFu + ((ae >> 20) & 1u);   // RNE at bit 20
  unsigned e = r >> 23;
  if (e < 121u) {                                   // |v| < 2^-6 -> fp8 subnormal
    float av = __uint_as_float(ae);
    unsigned m = (unsigned)__builtin_rintf(av * 512.0f);
    return s | m;                                   // m==8 rolls into exp=1 correctly
  }
  return s | ((e - 120u) << 3) | ((r >> 20) & 7u);
}
// Decode: HW cvt when available (exact), else software.
#if __has_builtin(__builtin_amdgcn_cvt_f32_fp8)
#define DEC4(w, x0, x1, x2, x3) \
  x0 += __builtin_amdgcn_cvt_f32_fp8((int)(w), 0); \
  x1 += __builtin_amdgcn_cvt_f32_fp8((int)(w), 1); \
  x2 += __builtin_amdgcn_cvt_f32_fp8((int)(w), 2); \
  x3 += __builtin_amdgcn_cvt_f32_fp8((int)(w), 3);
#else
__device__ inline float fp8dec(unsigned b) {
  unsigned s = (b & 0x80u) << 24;
  unsigned e = (b >> 3) & 0xFu;
  unsigned m = b & 7u;
  if (e == 0) { float f = (float)m * 0.001953125f; return s ? -f : f; }
  return __uint_as_float(s | ((e + 120u) << 23) | (m << 20));
}
#define DEC4(w, x0, x1, x2, x3) \
  x0 += fp8dec((w) & 0xffu); x1 += fp8dec(((w) >> 8) & 0xffu); \
  x2 += fp8dec(((w) >> 16) & 0xffu); x3 += fp8dec(((w) >> 24) & 0xffu);
#endif

// ---------- descriptors ----------
struct SortDesc {
  int tcum[9];
  int bcum[9];
  int gcum[8];
  int E[8];
  int n_dst[8];
  int wshift[8];
  int zrow[8];            // ROWS - src_base[r]: local sentinel -> global zero row
  const int* esrc[8];
  const int* edst[8];
};

struct AggrDesc {
  int cum[9];
  int src_base[8];
  int src_col[8];
  int dst_base[8];
  int dst_col[8];
  const float* demb[8];
};

// ---------- pass 1: bin edges into dst-range buckets ----------
__global__ __launch_bounds__(256) void part_kernel(SortDesc d, unsigned* __restrict__ pairs,
                                                   int* __restrict__ cursors) {
  __shared__ int cnt[256];
  __shared__ int lcur[256];
  int blk = blockIdx.x;
  int r = 0;
#pragma unroll
  for (int k = 1; k < 8; ++k) if (blk >= d.tcum[k]) r = k;
  int base = (blk - d.tcum[r]) * TILE;
  int n = min(TILE, d.E[r] - base);
  const int* __restrict__ esrc = d.esrc[r];
  const int* __restrict__ edst = d.edst[r];
  int tid = threadIdx.x;
  int B = d.bcum[r + 1] - d.bcum[r];
  int sh = d.wshift[r];
  int msk = (1 << sh) - 1;
  int bb = d.bcum[r];
  if (tid < B) cnt[tid] = 0;
  __syncthreads();
  for (int i = tid; i < n; i += 256)
    atomicAdd(&cnt[edst[base + i] >> sh], 1);
  __syncthreads();
  if (tid < B) {
    int c = cnt[tid];
    lcur[tid] = c ? atomicAdd(&cursors[bb + tid], c) : 0;
  }
  __syncthreads();
  for (int i = tid; i < n; i += 256) {
    int dv = edst[base + i];
    int sv = esrc[base + i];
    int b = dv >> sh;
    int pos = atomicAdd(&lcur[b], 1);
    if (pos < PCAP)
      pairs[(size_t)(bb + b) * PCAP + pos] = ((unsigned)(dv & msk) << 18) | (unsigned)sv;
  }
}

// ---------- pass 2: per-bucket counting sort in LDS with 8-padding ----------
__global__ __launch_bounds__(256) void build_kernel(SortDesc d, const unsigned* __restrict__ pairs,
                                                    const int* __restrict__ cursors,
                                                    int* __restrict__ gcounter,
                                                    int* __restrict__ sorted,
                                                    int* __restrict__ Beg, int* __restrict__ Deg) {
  __shared__ int cnt[1024];
  __shared__ int poff[1025];
  __shared__ int stage[SCAP];
  __shared__ int wsums[4];
  __shared__ int sh_gbase;
  int bucket = blockIdx.x;
  int r = 0;
#pragma unroll
  for (int k = 1; k < 8; ++k) if (bucket >= d.bcum[k]) r = k;
  int bl = bucket - d.bcum[r];
  int sh = d.wshift[r];
  int first = bl << sh;
  int Wa = min(1 << sh, d.n_dst[r] - first);
  int zr = d.zrow[r];
  int tid = threadIdx.x;
  int n_b = min(cursors[bucket], PCAP);
  const unsigned* __restrict__ bp = pairs + (size_t)bucket * PCAP;

  for (int i = tid; i < 1024; i += 256) cnt[i] = 0;
  __syncthreads();
  for (int i = tid; i < n_b; i += 256)
    atomicAdd(&cnt[bp[i] >> 18], 1);
  __syncthreads();

  int t4 = tid * 4;
  int c0 = cnt[t4], c1 = cnt[t4 + 1], c2 = cnt[t4 + 2], c3 = cnt[t4 + 3];
  int p0 = (c0 + 7) & ~7, p1 = (c1 + 7) & ~7, p2 = (c2 + 7) & ~7, p3 = (c3 + 7) & ~7;
  int s = p0 + p1 + p2 + p3;
  int lane = tid & 63, wv = tid >> 6;
  int v = s;
#pragma unroll
  for (int dd = 1; dd < 64; dd <<= 1) {
    int t = __shfl_up(v, dd);
    if (lane >= dd) v += t;
  }
  if (lane == 63) wsums[wv] = v;
  __syncthreads();
  if (tid == 0) {
    int run = 0;
#pragma unroll
    for (int k = 0; k < 4; ++k) { int t = wsums[k]; wsums[k] = run; run += t; }
  }
  __syncthreads();
  int ex = wsums[wv] + (v - s);
  if (tid == 255) {
    int tot = ex + s;
    sh_gbase = atomicAdd(gcounter, tot);
    poff[1024] = min(tot, SCAP);
  }
  __syncthreads();
  int gbase = sh_gbase;
  int o0 = ex, o1 = ex + p0, o2 = o1 + p1, o3 = o2 + p2;
  cnt[t4] = o0; cnt[t4 + 1] = o1; cnt[t4 + 2] = o2; cnt[t4 + 3] = o3;
  poff[t4] = o0; poff[t4 + 1] = o1; poff[t4 + 2] = o2; poff[t4 + 3] = o3;
  int g0 = d.gcum[r] + first + t4;
  if (t4 + 0 < Wa) { Beg[g0 + 0] = gbase + o0; Deg[g0 + 0] = c0; }
  if (t4 + 1 < Wa) { Beg[g0 + 1] = gbase + o1; Deg[g0 + 1] = c1; }
  if (t4 + 2 < Wa) { Beg[g0 + 2] = gbase + o2; Deg[g0 + 2] = c2; }
  if (t4 + 3 < Wa) { Beg[g0 + 3] = gbase + o3; Deg[g0 + 3] = c3; }
  __syncthreads();

  for (int i = tid; i < n_b; i += 256) {
    unsigned pr = bp[i];
    int pos = atomicAdd(&cnt[pr >> 18], 1);
    if (pos < SCAP) stage[pos] = (int)(pr & 0x3FFFFu);
  }
  __syncthreads();
#pragma unroll
  for (int jj = 0; jj < 4; ++jj) {
    int j = t4 + jj;
    int end_ = min((j < 1023) ? poff[j + 1] : poff[1024], SCAP);
    for (int k = cnt[j]; k < end_; ++k) stage[k] = zr;
  }
  __syncthreads();

  int tot = poff[1024];
  for (int i = tid; i < tot; i += 256)
    sorted[gbase + i] = stage[i];
}

// ---------- f32 inputs -> bf16 feature buffer + zero row in both buffers ----------
__global__ void convert_kernel(const float* __restrict__ u, const float* __restrict__ v,
                               const float* __restrict__ p, const float* __restrict__ t,
                               uint16_t* __restrict__ featA, uint16_t* __restrict__ featB) {
  int idx = blockIdx.x * blockDim.x + threadIdx.x;
  const int total8 = (ROWS + 1) * EMB / 8;
  if (idx >= total8) return;
  int flat = idx * 8;
  int row = flat >> 7;
  if (row == ROWS) {
    uint4 z = {0u, 0u, 0u, 0u};
    *(uint4*)(featA + flat) = z;
    *(uint4*)(featB + flat) = z;
    return;
  }
  int col = flat & 127;
  const float* s;
  if (row < ROW_V)      s = u + (size_t)row * EMB + col;
  else if (row < ROW_P) s = v + (size_t)(row - ROW_V) * EMB + col;
  else if (row < ROW_T) s = p + (size_t)(row - ROW_P) * EMB + col;
  else                  s = t + (size_t)(row - ROW_T) * EMB + col;
  float4 f0 = *(const float4*)s;
  float4 f1 = *((const float4*)s + 1);
  uint4 o;
  o.x = pack_bf16x2(f0.x, f0.y);
  o.y = pack_bf16x2(f0.z, f0.w);
  o.z = pack_bf16x2(f1.x, f1.y);
  o.w = pack_bf16x2(f1.z, f1.w);
  *(uint4*)(featA + flat) = o;
}

// ---------- hot kernel ----------
// MODE 0: gather bf16 -> write bf16 (NT).        (layer 0: f1)
// MODE 1: gather bf16 -> write fp8 (NT).         (layer 1: f2, fp8-only)
// MODE 2: gather fp8  -> fused epilogue:         out = demb + 1/2 f1 + 1/3 f2 + 1/4 f3
#define ACC(q) \
  a0 += __uint_as_float((q).x << 16); a1 += __uint_as_float((q).x & 0xffff0000u); \
  a2 += __uint_as_float((q).y << 16); a3 += __uint_as_float((q).y & 0xffff0000u); \
  a4 += __uint_as_float((q).z << 16); a5 += __uint_as_float((q).z & 0xffff0000u); \
  a6 += __uint_as_float((q).w << 16); a7 += __uint_as_float((q).w & 0xffff0000u);

#define ACC8(qq) \
  DEC4((qq).x, a0, a1, a2, a3); DEC4((qq).y, a4, a5, a6, a7);

template<int MODE>
__global__ __launch_bounds__(256) void aggr_kernel(AggrDesc d,
    const uint16_t* __restrict__ gsrc_bf, const unsigned char* __restrict__ gsrc_f8,
    uint16_t* __restrict__ dst_bf, unsigned char* __restrict__ dst_f8,
    const uint16_t* __restrict__ f1_bf, float* __restrict__ out,
    const int* __restrict__ sorted, const int* __restrict__ Beg,
    const int* __restrict__ Deg) {
  if (MODE == 1 && blockIdx.x == 0 && threadIdx.x < 16) {
    // zero row for layer-2 pad gathers (no dst writes row ROWS)
    uint2 z = {0u, 0u};
    *(uint2*)(dst_f8 + (size_t)ROWS * EMB + threadIdx.x * 8) = z;
  }
  int g = blockIdx.x * 32 + (threadIdx.x >> 3);
  if (g >= TOTAL_GROUPS) return;
  int lane = threadIdx.x & 7;
  int r = 0;
#pragma unroll
  for (int k = 1; k < 8; ++k) if (g >= d.cum[k]) r = k;
  int n = g - d.cum[r];
  int beg = Beg[g], dg = Deg[g];
  float recip = 1.0f / (float)(dg > 0 ? dg : 1);
  const uint16_t* __restrict__ sb16 =
      gsrc_bf ? gsrc_bf + (size_t)d.src_base[r] * EMB + d.src_col[r] + lane * 8 : nullptr;
  const unsigned char* __restrict__ sb8 =
      gsrc_f8 ? gsrc_f8 + (size_t)d.src_base[r] * EMB + d.src_col[r] + lane * 8 : nullptr;
  float a0 = 0.f, a1 = 0.f, a2 = 0.f, a3 = 0.f, a4 = 0.f, a5 = 0.f, a6 = 0.f, a7 = 0.f;
  int nchunk = (dg + 7) >> 3;
  const int* ep = sorted + beg;           // beg is 8-aligned -> int4 loads aligned
  int4 iA0 = {0,0,0,0}, iA1 = {0,0,0,0};
  if (nchunk > 0) { iA0 = *(const int4*)ep; iA1 = *(const int4*)(ep + 4); }
  for (int c = 0; c < nchunk; ++c) {
    int4 iB0 = {0,0,0,0}, iB1 = {0,0,0,0};
    if (c + 1 < nchunk) { iB0 = *(const int4*)(ep + 8); iB1 = *(const int4*)(ep + 12); }
    if (MODE < 2) {
      uint4 q0 = *(const uint4*)(sb16 + (size_t)iA0.x * EMB);
      uint4 q1 = *(const uint4*)(sb16 + (size_t)iA0.y * EMB);
      uint4 q2 = *(const uint4*)(sb16 + (size_t)iA0.z * EMB);
      uint4 q3 = *(const uint4*)(sb16 + (size_t)iA0.w * EMB);
      uint4 q4 = *(const uint4*)(sb16 + (size_t)iA1.x * EMB);
      uint4 q5 = *(const uint4*)(sb16 + (size_t)iA1.y * EMB);
      uint4 q6 = *(const uint4*)(sb16 + (size_t)iA1.z * EMB);
      uint4 q7 = *(const uint4*)(sb16 + (size_t)iA1.w * EMB);
      __builtin_amdgcn_sched_barrier(0);
      ACC(q0); ACC(q1); ACC(q2); ACC(q3);
      ACC(q4); ACC(q5); ACC(q6); ACC(q7);
    } else {
      uint2 q0 = *(const uint2*)(sb8 + (size_t)iA0.x * EMB);
      uint2 q1 = *(const uint2*)(sb8 + (size_t)iA0.y * EMB);
      uint2 q2 = *(const uint2*)(sb8 + (size_t)iA0.z * EMB);
      uint2 q3 = *(const uint2*)(sb8 + (size_t)iA0.w * EMB);
      uint2 q4 = *(const uint2*)(sb8 + (size_t)iA1.x * EMB);
      uint2 q5 = *(const uint2*)(sb8 + (size_t)iA1.y * EMB);
      uint2 q6 = *(const uint2*)(sb8 + (size_t)iA1.z * EMB);
      uint2 q7 = *(const uint2*)(sb8 + (size_t)iA1.w * EMB);
      __builtin_amdgcn_sched_barrier(0);
      ACC8(q0); ACC8(q1); ACC8(q2); ACC8(q3);
      ACC8(q4); ACC8(q5); ACC8(q6); ACC8(q7);
    }
    iA0 = iB0; iA1 = iB1; ep += 8;
  }
  a0 *= recip; a1 *= recip; a2 *= recip; a3 *= recip;
  a4 *= recip; a5 *= recip; a6 *= recip; a7 *= recip;

  int col = d.dst_col[r] + lane * 8;
  size_t dpos = (size_t)(d.dst_base[r] + n) * EMB + col;

  if (MODE == 0) {
    u32x4 ov;
    ov.x = pack_bf16x2(a0, a1);
    ov.y = pack_bf16x2(a2, a3);
    ov.z = pack_bf16x2(a4, a5);
    ov.w = pack_bf16x2(a6, a7);
    __builtin_nontemporal_store(ov, (u32x4*)(dst_bf + dpos));
    return;
  }
  if (MODE == 1) {
    u32x2 ov;
    ov.x = fp8enc(a0) | (fp8enc(a1) << 8) | (fp8enc(a2) << 16) | (fp8enc(a3) << 24);
    ov.y = fp8enc(a4) | (fp8enc(a5) << 8) | (fp8enc(a6) << 16) | (fp8enc(a7) << 24);
    __builtin_nontemporal_store(ov, (u32x2*)(dst_f8 + dpos));
    return;
  }

  // MODE 2 final epilogue
  u32x4 q1 = __builtin_nontemporal_load((const u32x4*)(f1_bf + dpos));   // f1 bf16
  u32x2 qf = __builtin_nontemporal_load((const u32x2*)(gsrc_f8 + dpos)); // f2 fp8
  float g0 = 0.f, g1 = 0.f, g2 = 0.f, g3 = 0.f, g4 = 0.f, g5 = 0.f, g6 = 0.f, g7 = 0.f;
  DEC4(qf.x, g0, g1, g2, g3);
  DEC4(qf.y, g4, g5, g6, g7);
  const f32x4* de = (const f32x4*)(d.demb[r] + (size_t)n * EMB + col);
  f32x4 v0 = __builtin_nontemporal_load(de);
  f32x4 v1 = __builtin_nontemporal_load(de + 1);
  const float w1 = 0.5f, w2 = 1.0f / 3.0f, w3 = 0.25f;
  v0.x += w1 * __uint_as_float(q1.x << 16)         + w2 * g0 + w3 * a0;
  v0.y += w1 * __uint_as_float(q1.x & 0xffff0000u) + w2 * g1 + w3 * a1;
  v0.z += w1 * __uint_as_float(q1.y << 16)         + w2 * g2 + w3 * a2;
  v0.w += w1 * __uint_as_float(q1.y & 0xffff0000u) + w2 * g3 + w3 * a3;
  v1.x += w1 * __uint_as_float(q1.z << 16)         + w2 * g4 + w3 * a4;
  v1.y += w1 * __uint_as_float(q1.z & 0xffff0000u) + w2 * g5 + w3 * a5;
  v1.z += w1 * __uint_as_float(q1.w << 16)         + w2 * g6 + w3 * a6;
  v1.w += w1 * __uint_as_float(q1.w & 0xffff0000u) + w2 * g7 + w3 * a7;
  __builtin_nontemporal_store(v0, (f32x4*)(out + dpos));
  __builtin_nontemporal_store(v1, (f32x4*)(out + dpos) + 1);
}

// ---------- host ----------
extern "C" void kernel_launch(void* const* d_in, const int* in_sizes, int n_in,
                              void* d_out, int out_size, void* d_ws, size_t ws_size,
                              hipStream_t stream) {
  const float* emb_u = (const float*)d_in[0];
  const float* emb_v = (const float*)d_in[1];
  const float* emb_p = (const float*)d_in[2];
  const float* emb_t = (const float*)d_in[3];

  struct RelInfo { int si, di, E, n_dst, src_base, src_col, dst_base, dst_col, wshift; };
  const RelInfo rels[8] = {
    {12, 13,  800000, N_TAG,   ROW_V, 64, ROW_T,  0,  5},  // vt
    {16, 17,  400000, N_TAG,   ROW_P, 64, ROW_T, 64,  5},  // pt
    { 8,  9,  800000, N_PUB,   ROW_U, 64, ROW_P,  0,  7},  // up
    {18, 19,  400000, N_PUB,   ROW_T, 64, ROW_P, 64,  7},  // tp
    { 4,  5, 1500000, N_VIDEO, ROW_U,  0, ROW_V,  0,  9},  // uv
    {14, 15,  800000, N_VIDEO, ROW_T,  0, ROW_V, 64,  9},  // tv
    { 6,  7, 1500000, N_USER,  ROW_V,  0, ROW_U,  0, 10},  // vu
    {10, 11,  800000, N_USER,  ROW_P,  0, ROW_U, 64, 10},  // pu
  };
  const float* dembs[8] = {emb_t, emb_t, emb_p, emb_p, emb_v, emb_v, emb_u, emb_u};

  char* ws = (char*)d_ws;
  size_t cursor = 0;
  auto take = [&](size_t bytes) -> char* {
    char* p = ws + cursor;
    cursor = (cursor + bytes + 255) & ~(size_t)255;
    return p;
  };
  uint16_t* featA = (uint16_t*)take((size_t)(ROWS + 1) * EMB * 2);
  uint16_t* featB = (uint16_t*)take((size_t)(ROWS + 1) * EMB * 2);
  int* sorted = (int*)take((size_t)SORT_MAX * 4);
  int* Beg    = (int*)take((size_t)TOTAL_GROUPS * 4);
  int* Deg    = (int*)take((size_t)TOTAL_GROUPS * 4);
  unsigned* pairs = (unsigned*)d_ws;                    // alias over featA/featB (dead before convert)
  unsigned char* f2fp8 = (unsigned char*)featA;         // alias over featA (dead after layer 0)

  SortDesc sd;
  AggrDesc ad;
  int tacc = 0, bacc = 0, gacc = 0;
  for (int r = 0; r < 8; ++r) {
    int n_dst = rels[r].n_dst;
    sd.tcum[r] = tacc; tacc += (rels[r].E + TILE - 1) / TILE;
    sd.bcum[r] = bacc; bacc += (n_dst + (1 << rels[r].wshift) - 1) >> rels[r].wshift;
    sd.gcum[r] = gacc;
    sd.E[r] = rels[r].E;
    sd.n_dst[r] = n_dst;
    sd.wshift[r] = rels[r].wshift;
    sd.zrow[r] = ROWS - rels[r].src_base;
    sd.esrc[r] = (const int*)d_in[rels[r].si];
    sd.edst[r] = (const int*)d_in[rels[r].di];

    ad.cum[r] = gacc;
    ad.src_base[r] = rels[r].src_base;
    ad.src_col[r] = rels[r].src_col;
    ad.dst_base[r] = rels[r].dst_base;
    ad.dst_col[r] = rels[r].dst_col;
    ad.demb[r] = dembs[r];
    gacc += n_dst;
  }
  sd.tcum[8] = tacc;
  sd.bcum[8] = bacc;
  ad.cum[8] = gacc;    // 650000

  int* cursors  = (int*)take((size_t)bacc * 4 + 4);
  int* gcounter = cursors + bacc;

  // ---- CSR build (padded to multiples of 8 per dst)
  hipMemsetAsync(cursors, 0, (size_t)(bacc + 1) * 4, stream);
  part_kernel<<<tacc, 256, 0, stream>>>(sd, pairs, cursors);
  build_kernel<<<bacc, 256, 0, stream>>>(sd, pairs, cursors, gcounter, sorted, Beg, Deg);

  // ---- bf16 feature init (pairs region dead) + zero rows
  convert_kernel<<<((ROWS + 1) * EMB / 8 + 255) / 256, 256, 0, stream>>>(
      emb_u, emb_v, emb_p, emb_t, featA, featB);

  float* out = (float*)d_out;
  const int aggr_blocks = (TOTAL_GROUPS + 31) / 32;
  // layer 0: featA(bf16 input) -> featB = f1 (bf16)
  aggr_kernel<0><<<aggr_blocks, 256, 0, stream>>>(ad, featA, nullptr, featB, nullptr,
                                                  nullptr, nullptr, sorted, Beg, Deg);
  // layer 1: featB(f1) -> f2fp8 = f2 (fp8, overwrites dead featA)
  aggr_kernel<1><<<aggr_blocks, 256, 0, stream>>>(ad, featB, nullptr, nullptr, f2fp8,
                                                  nullptr, nullptr, sorted, Beg, Deg);
  // layer 2: gather f2fp8 -> f3 in regs; out = demb + 1/2 f1 + 1/3 f2 + 1/4 f3
  aggr_kernel<2><<<aggr_blocks, 256, 0, stream>>>(ad, nullptr, f2fp8, nullptr, nullptr,
                                                  featB, out, sorted, Beg, Deg);
}

// Round 7
// 599.613 us; speedup vs baseline: 3.8522x; 1.0107x over previous
//
#include <hip/hip_runtime.h>
#include <stdint.h>

#define EMB 128
#define PCAP 12288          // pairs stride per bucket (real edges; avg <=7700)
#define SCAP 13312          // stage capacity (padded edges per bucket)

static constexpr int N_USER = 200000, N_VIDEO = 100000, N_PUB = 20000, N_TAG = 5000;
static constexpr int ROW_U = 0, ROW_V = 200000, ROW_P = 300000, ROW_T = 320000;
static constexpr int ROWS = 325000;           // + 1 extra zero row at index ROWS
static constexpr int TOTAL_E = 7000000;
static constexpr int TOTAL_GROUPS = 650000;
static constexpr int TILE = 8192;
static constexpr int SORT_MAX = TOTAL_E + 7 * TOTAL_GROUPS;

using f32x4 = __attribute__((ext_vector_type(4))) float;
using u32x4 = __attribute__((ext_vector_type(4))) unsigned int;
using u32x2 = __attribute__((ext_vector_type(2))) unsigned int;

// ---------- bf16 helpers ----------
__device__ inline unsigned bf16_rne(float f) {
  unsigned u = __float_as_uint(f);
  return (u + 0x7fffu + ((u >> 16) & 1u)) >> 16;
}
__device__ inline unsigned pack_bf16x2(float lo, float hi) {
  return bf16_rne(lo) | (bf16_rne(hi) << 16);
}

// ---------- fp8 e4m3fn helpers ----------
__device__ inline unsigned fp8enc(float f) {
  unsigned b = __float_as_uint(f);
  unsigned s = (b >> 24) & 0x80u;
  unsigned ae = b & 0x7FFFFFFFu;
  unsigned r = ae + 0x7FFFFu + ((ae >> 20) & 1u);   // RNE at bit 20
  unsigned e = r >> 23;
  if (e < 121u) {                                   // |v| < 2^-6 -> fp8 subnormal
    float av = __uint_as_float(ae);
    unsigned m = (unsigned)__builtin_rintf(av * 512.0f);
    return s | m;
  }
  return s | ((e - 120u) << 3) | ((r >> 20) & 7u);
}
#if __has_builtin(__builtin_amdgcn_cvt_f32_fp8)
#define DEC4(w, x0, x1, x2, x3) \
  x0 += __builtin_amdgcn_cvt_f32_fp8((int)(w), 0); \
  x1 += __builtin_amdgcn_cvt_f32_fp8((int)(w), 1); \
  x2 += __builtin_amdgcn_cvt_f32_fp8((int)(w), 2); \
  x3 += __builtin_amdgcn_cvt_f32_fp8((int)(w), 3);
#else
__device__ inline float fp8dec(unsigned b) {
  unsigned s = (b & 0x80u) << 24;
  unsigned e = (b >> 3) & 0xFu;
  unsigned m = b & 7u;
  if (e == 0) { float f = (float)m * 0.001953125f; return s ? -f : f; }
  return __uint_as_float(s | ((e + 120u) << 23) | (m << 20));
}
#define DEC4(w, x0, x1, x2, x3) \
  x0 += fp8dec((w) & 0xffu); x1 += fp8dec(((w) >> 8) & 0xffu); \
  x2 += fp8dec(((w) >> 16) & 0xffu); x3 += fp8dec(((w) >> 24) & 0xffu);
#endif

// ---------- descriptors ----------
struct SortDesc {
  int tcum[9];
  int bcum[9];
  int gcum[8];
  int E[8];
  int n_dst[8];
  int wshift[8];
  int zrow[8];            // ROWS - src_base[r]: local sentinel -> global zero row
  const int* esrc[8];
  const int* edst[8];
};

struct AggrDesc {
  int cum[9];
  int src_base[8];
  int src_col[8];
  int dst_base[8];
  int dst_col[8];
  const float* demb[8];
};

// ---------- pass 1: bin edges into dst-range buckets ----------
__global__ __launch_bounds__(256) void part_kernel(SortDesc d, unsigned* __restrict__ pairs,
                                                   int* __restrict__ cursors) {
  __shared__ int cnt[256];
  __shared__ int lcur[256];
  int blk = blockIdx.x;
  int r = 0;
#pragma unroll
  for (int k = 1; k < 8; ++k) if (blk >= d.tcum[k]) r = k;
  int base = (blk - d.tcum[r]) * TILE;
  int n = min(TILE, d.E[r] - base);
  const int* __restrict__ esrc = d.esrc[r];
  const int* __restrict__ edst = d.edst[r];
  int tid = threadIdx.x;
  int B = d.bcum[r + 1] - d.bcum[r];
  int sh = d.wshift[r];
  int msk = (1 << sh) - 1;
  int bb = d.bcum[r];
  if (tid < B) cnt[tid] = 0;
  __syncthreads();
  for (int i = tid; i < n; i += 256)
    atomicAdd(&cnt[edst[base + i] >> sh], 1);
  __syncthreads();
  if (tid < B) {
    int c = cnt[tid];
    lcur[tid] = c ? atomicAdd(&cursors[bb + tid], c) : 0;
  }
  __syncthreads();
  for (int i = tid; i < n; i += 256) {
    int dv = edst[base + i];
    int sv = esrc[base + i];
    int b = dv >> sh;
    int pos = atomicAdd(&lcur[b], 1);
    if (pos < PCAP)
      pairs[(size_t)(bb + b) * PCAP + pos] = ((unsigned)(dv & msk) << 18) | (unsigned)sv;
  }
}

// ---------- pass 2: per-bucket counting sort in LDS with 8-padding ----------
__global__ __launch_bounds__(256) void build_kernel(SortDesc d, const unsigned* __restrict__ pairs,
                                                    const int* __restrict__ cursors,
                                                    int* __restrict__ gcounter,
                                                    int* __restrict__ sorted,
                                                    int* __restrict__ Beg, int* __restrict__ Deg) {
  __shared__ int cnt[1024];
  __shared__ int poff[1025];
  __shared__ int stage[SCAP];
  __shared__ int wsums[4];
  __shared__ int sh_gbase;
  int bucket = blockIdx.x;
  int r = 0;
#pragma unroll
  for (int k = 1; k < 8; ++k) if (bucket >= d.bcum[k]) r = k;
  int bl = bucket - d.bcum[r];
  int sh = d.wshift[r];
  int first = bl << sh;
  int Wa = min(1 << sh, d.n_dst[r] - first);
  int zr = d.zrow[r];
  int tid = threadIdx.x;
  int n_b = min(cursors[bucket], PCAP);
  const unsigned* __restrict__ bp = pairs + (size_t)bucket * PCAP;

  for (int i = tid; i < 1024; i += 256) cnt[i] = 0;
  __syncthreads();
  for (int i = tid; i < n_b; i += 256)
    atomicAdd(&cnt[bp[i] >> 18], 1);
  __syncthreads();

  int t4 = tid * 4;
  int c0 = cnt[t4], c1 = cnt[t4 + 1], c2 = cnt[t4 + 2], c3 = cnt[t4 + 3];
  int p0 = (c0 + 7) & ~7, p1 = (c1 + 7) & ~7, p2 = (c2 + 7) & ~7, p3 = (c3 + 7) & ~7;
  int s = p0 + p1 + p2 + p3;
  int lane = tid & 63, wv = tid >> 6;
  int v = s;
#pragma unroll
  for (int dd = 1; dd < 64; dd <<= 1) {
    int t = __shfl_up(v, dd);
    if (lane >= dd) v += t;
  }
  if (lane == 63) wsums[wv] = v;
  __syncthreads();
  if (tid == 0) {
    int run = 0;
#pragma unroll
    for (int k = 0; k < 4; ++k) { int t = wsums[k]; wsums[k] = run; run += t; }
  }
  __syncthreads();
  int ex = wsums[wv] + (v - s);
  if (tid == 255) {
    int tot = ex + s;
    sh_gbase = atomicAdd(gcounter, tot);
    poff[1024] = min(tot, SCAP);
  }
  __syncthreads();
  int gbase = sh_gbase;
  int o0 = ex, o1 = ex + p0, o2 = o1 + p1, o3 = o2 + p2;
  cnt[t4] = o0; cnt[t4 + 1] = o1; cnt[t4 + 2] = o2; cnt[t4 + 3] = o3;
  poff[t4] = o0; poff[t4 + 1] = o1; poff[t4 + 2] = o2; poff[t4 + 3] = o3;
  int g0 = d.gcum[r] + first + t4;
  if (t4 + 0 < Wa) { Beg[g0 + 0] = gbase + o0; Deg[g0 + 0] = c0; }
  if (t4 + 1 < Wa) { Beg[g0 + 1] = gbase + o1; Deg[g0 + 1] = c1; }
  if (t4 + 2 < Wa) { Beg[g0 + 2] = gbase + o2; Deg[g0 + 2] = c2; }
  if (t4 + 3 < Wa) { Beg[g0 + 3] = gbase + o3; Deg[g0 + 3] = c3; }
  __syncthreads();

  for (int i = tid; i < n_b; i += 256) {
    unsigned pr = bp[i];
    int pos = atomicAdd(&cnt[pr >> 18], 1);
    if (pos < SCAP) stage[pos] = (int)(pr & 0x3FFFFu);
  }
  __syncthreads();
#pragma unroll
  for (int jj = 0; jj < 4; ++jj) {
    int j = t4 + jj;
    int end_ = min((j < 1023) ? poff[j + 1] : poff[1024], SCAP);
    for (int k = cnt[j]; k < end_; ++k) stage[k] = zr;
  }
  __syncthreads();

  int tot = poff[1024];
  for (int i = tid; i < tot; i += 256)
    sorted[gbase + i] = stage[i];
}

// ---------- f32 inputs -> bf16 feature buffer + zero rows ----------
__global__ void convert_kernel(const float* __restrict__ u, const float* __restrict__ v,
                               const float* __restrict__ p, const float* __restrict__ t,
                               uint16_t* __restrict__ featA, uint16_t* __restrict__ featB,
                               unsigned char* __restrict__ f1f8) {
  int idx = blockIdx.x * blockDim.x + threadIdx.x;
  const int total8 = (ROWS + 1) * EMB / 8;
  if (idx >= total8) return;
  int flat = idx * 8;
  int row = flat >> 7;
  if (row == ROWS) {
    uint4 z = {0u, 0u, 0u, 0u};
    *(uint4*)(featA + flat) = z;
    *(uint4*)(featB + flat) = z;
    if (f1f8) { uint2 z2 = {0u, 0u}; *(uint2*)(f1f8 + flat) = z2; }
    return;
  }
  int col = flat & 127;
  const float* s;
  if (row < ROW_V)      s = u + (size_t)row * EMB + col;
  else if (row < ROW_P) s = v + (size_t)(row - ROW_V) * EMB + col;
  else if (row < ROW_T) s = p + (size_t)(row - ROW_P) * EMB + col;
  else                  s = t + (size_t)(row - ROW_T) * EMB + col;
  float4 f0 = *(const float4*)s;
  float4 f1 = *((const float4*)s + 1);
  uint4 o;
  o.x = pack_bf16x2(f0.x, f0.y);
  o.y = pack_bf16x2(f0.z, f0.w);
  o.z = pack_bf16x2(f1.x, f1.y);
  o.w = pack_bf16x2(f1.z, f1.w);
  *(uint4*)(featA + flat) = o;
}

// ---------- hot kernel ----------
// M=0: gather bf16 -> write bf16                    (layer0, no-fp8 fallback)
// M=4: gather bf16 -> write bf16 + fp8 dual        (layer0, fp8 path)
// M=3: gather bf16 -> write fp8                    (layer1 fallback)
// M=1: gather fp8  -> write fp8                    (layer1 fp8 path)
// M=2: gather fp8  -> epilogue out = emb + 1/2 f1 + 1/3 f2 + 1/4 f3
#define ACC(q) \
  a0 += __uint_as_float((q).x << 16); a1 += __uint_as_float((q).x & 0xffff0000u); \
  a2 += __uint_as_float((q).y << 16); a3 += __uint_as_float((q).y & 0xffff0000u); \
  a4 += __uint_as_float((q).z << 16); a5 += __uint_as_float((q).z & 0xffff0000u); \
  a6 += __uint_as_float((q).w << 16); a7 += __uint_as_float((q).w & 0xffff0000u);

#define ACC8(qq) \
  DEC4((qq).x, a0, a1, a2, a3); DEC4((qq).y, a4, a5, a6, a7);

template<int M>
__global__ __launch_bounds__(256) void aggr_kernel(AggrDesc d,
    const uint16_t* __restrict__ gsrc_bf, const unsigned char* __restrict__ gsrc_f8,
    uint16_t* __restrict__ dst_bf, unsigned char* __restrict__ dst_f8,
    const uint16_t* __restrict__ f1_bf, const uint16_t* __restrict__ demb_bf,
    float* __restrict__ out,
    const int* __restrict__ sorted, const int* __restrict__ Beg,
    const int* __restrict__ Deg) {
  if ((M == 1 || M == 3) && blockIdx.x == 0 && threadIdx.x < 16) {
    // zero row of f2fp8 for layer-2 pad gathers
    uint2 z = {0u, 0u};
    *(uint2*)(dst_f8 + (size_t)ROWS * EMB + threadIdx.x * 8) = z;
  }
  int g = blockIdx.x * 32 + (threadIdx.x >> 3);
  if (g >= TOTAL_GROUPS) return;
  int lane = threadIdx.x & 7;
  int r = 0;
#pragma unroll
  for (int k = 1; k < 8; ++k) if (g >= d.cum[k]) r = k;
  int n = g - d.cum[r];
  int beg = Beg[g], dg = Deg[g];
  float recip = 1.0f / (float)(dg > 0 ? dg : 1);
  constexpr bool GB = (M == 0 || M == 3 || M == 4);   // gather bf16?
  const uint16_t* __restrict__ sb16 =
      GB ? gsrc_bf + (size_t)d.src_base[r] * EMB + d.src_col[r] + lane * 8 : nullptr;
  const unsigned char* __restrict__ sb8 =
      !GB ? gsrc_f8 + (size_t)d.src_base[r] * EMB + d.src_col[r] + lane * 8 : nullptr;
  float a0 = 0.f, a1 = 0.f, a2 = 0.f, a3 = 0.f, a4 = 0.f, a5 = 0.f, a6 = 0.f, a7 = 0.f;
  int nchunk = (dg + 7) >> 3;
  const int* ep = sorted + beg;           // beg is 8-aligned
  int4 iA0 = {0,0,0,0}, iA1 = {0,0,0,0};
  if (nchunk > 0) { iA0 = *(const int4*)ep; iA1 = *(const int4*)(ep + 4); }
  for (int c = 0; c < nchunk; ++c) {
    int4 iB0 = {0,0,0,0}, iB1 = {0,0,0,0};
    if (c + 1 < nchunk) { iB0 = *(const int4*)(ep + 8); iB1 = *(const int4*)(ep + 12); }
    if (GB) {
      uint4 q0 = *(const uint4*)(sb16 + (size_t)iA0.x * EMB);
      uint4 q1 = *(const uint4*)(sb16 + (size_t)iA0.y * EMB);
      uint4 q2 = *(const uint4*)(sb16 + (size_t)iA0.z * EMB);
      uint4 q3 = *(const uint4*)(sb16 + (size_t)iA0.w * EMB);
      uint4 q4 = *(const uint4*)(sb16 + (size_t)iA1.x * EMB);
      uint4 q5 = *(const uint4*)(sb16 + (size_t)iA1.y * EMB);
      uint4 q6 = *(const uint4*)(sb16 + (size_t)iA1.z * EMB);
      uint4 q7 = *(const uint4*)(sb16 + (size_t)iA1.w * EMB);
      __builtin_amdgcn_sched_barrier(0);
      ACC(q0); ACC(q1); ACC(q2); ACC(q3);
      ACC(q4); ACC(q5); ACC(q6); ACC(q7);
    } else {
      uint2 q0 = *(const uint2*)(sb8 + (size_t)iA0.x * EMB);
      uint2 q1 = *(const uint2*)(sb8 + (size_t)iA0.y * EMB);
      uint2 q2 = *(const uint2*)(sb8 + (size_t)iA0.z * EMB);
      uint2 q3 = *(const uint2*)(sb8 + (size_t)iA0.w * EMB);
      uint2 q4 = *(const uint2*)(sb8 + (size_t)iA1.x * EMB);
      uint2 q5 = *(const uint2*)(sb8 + (size_t)iA1.y * EMB);
      uint2 q6 = *(const uint2*)(sb8 + (size_t)iA1.z * EMB);
      uint2 q7 = *(const uint2*)(sb8 + (size_t)iA1.w * EMB);
      __builtin_amdgcn_sched_barrier(0);
      ACC8(q0); ACC8(q1); ACC8(q2); ACC8(q3);
      ACC8(q4); ACC8(q5); ACC8(q6); ACC8(q7);
    }
    iA0 = iB0; iA1 = iB1; ep += 8;
  }
  a0 *= recip; a1 *= recip; a2 *= recip; a3 *= recip;
  a4 *= recip; a5 *= recip; a6 *= recip; a7 *= recip;

  int col = d.dst_col[r] + lane * 8;
  size_t dpos = (size_t)(d.dst_base[r] + n) * EMB + col;

  if (M == 0 || M == 4) {
    u32x4 ov;
    ov.x = pack_bf16x2(a0, a1);
    ov.y = pack_bf16x2(a2, a3);
    ov.z = pack_bf16x2(a4, a5);
    ov.w = pack_bf16x2(a6, a7);
    __builtin_nontemporal_store(ov, (u32x4*)(dst_bf + dpos));
    if (M == 4) {
      u32x2 o8;
      o8.x = fp8enc(a0) | (fp8enc(a1) << 8) | (fp8enc(a2) << 16) | (fp8enc(a3) << 24);
      o8.y = fp8enc(a4) | (fp8enc(a5) << 8) | (fp8enc(a6) << 16) | (fp8enc(a7) << 24);
      __builtin_nontemporal_store(o8, (u32x2*)(dst_f8 + dpos));
    }
    return;
  }
  if (M == 1 || M == 3) {
    u32x2 ov;
    ov.x = fp8enc(a0) | (fp8enc(a1) << 8) | (fp8enc(a2) << 16) | (fp8enc(a3) << 24);
    ov.y = fp8enc(a4) | (fp8enc(a5) << 8) | (fp8enc(a6) << 16) | (fp8enc(a7) << 24);
    __builtin_nontemporal_store(ov, (u32x2*)(dst_f8 + dpos));
    return;
  }

  // M == 2: final epilogue
  u32x4 q1 = __builtin_nontemporal_load((const u32x4*)(f1_bf + dpos));   // f1 bf16
  u32x2 qf = __builtin_nontemporal_load((const u32x2*)(gsrc_f8 + dpos)); // f2 fp8
  float g0 = 0.f, g1 = 0.f, g2 = 0.f, g3 = 0.f, g4 = 0.f, g5 = 0.f, g6 = 0.f, g7 = 0.f;
  DEC4(qf.x, g0, g1, g2, g3);
  DEC4(qf.y, g4, g5, g6, g7);
  f32x4 v0, v1;
  if (demb_bf) {          // bf16 input copy (tier 3): 83MB instead of 166MB
    u32x4 qe = __builtin_nontemporal_load((const u32x4*)(demb_bf + dpos));
    v0.x = __uint_as_float(qe.x << 16); v0.y = __uint_as_float(qe.x & 0xffff0000u);
    v0.z = __uint_as_float(qe.y << 16); v0.w = __uint_as_float(qe.y & 0xffff0000u);
    v1.x = __uint_as_float(qe.z << 16); v1.y = __uint_as_float(qe.z & 0xffff0000u);
    v1.z = __uint_as_float(qe.w << 16); v1.w = __uint_as_float(qe.w & 0xffff0000u);
  } else {
    const f32x4* de = (const f32x4*)(d.demb[r] + (size_t)n * EMB + col);
    v0 = __builtin_nontemporal_load(de);
    v1 = __builtin_nontemporal_load(de + 1);
  }
  const float w1 = 0.5f, w2 = 1.0f / 3.0f, w3 = 0.25f;
  v0.x += w1 * __uint_as_float(q1.x << 16)         + w2 * g0 + w3 * a0;
  v0.y += w1 * __uint_as_float(q1.x & 0xffff0000u) + w2 * g1 + w3 * a1;
  v0.z += w1 * __uint_as_float(q1.y << 16)         + w2 * g2 + w3 * a2;
  v0.w += w1 * __uint_as_float(q1.y & 0xffff0000u) + w2 * g3 + w3 * a3;
  v1.x += w1 * __uint_as_float(q1.z << 16)         + w2 * g4 + w3 * a4;
  v1.y += w1 * __uint_as_float(q1.z & 0xffff0000u) + w2 * g5 + w3 * a5;
  v1.z += w1 * __uint_as_float(q1.w << 16)         + w2 * g6 + w3 * a6;
  v1.w += w1 * __uint_as_float(q1.w & 0xffff0000u) + w2 * g7 + w3 * a7;
  __builtin_nontemporal_store(v0, (f32x4*)(out + dpos));
  __builtin_nontemporal_store(v1, (f32x4*)(out + dpos) + 1);
}

// ---------- host ----------
extern "C" void kernel_launch(void* const* d_in, const int* in_sizes, int n_in,
                              void* d_out, int out_size, void* d_ws, size_t ws_size,
                              hipStream_t stream) {
  const float* emb_u = (const float*)d_in[0];
  const float* emb_v = (const float*)d_in[1];
  const float* emb_p = (const float*)d_in[2];
  const float* emb_t = (const float*)d_in[3];

  struct RelInfo { int si, di, E, n_dst, src_base, src_col, dst_base, dst_col, wshift; };
  const RelInfo rels[8] = {
    {12, 13,  800000, N_TAG,   ROW_V, 64, ROW_T,  0,  5},  // vt
    {16, 17,  400000, N_TAG,   ROW_P, 64, ROW_T, 64,  5},  // pt
    { 8,  9,  800000, N_PUB,   ROW_U, 64, ROW_P,  0,  7},  // up
    {18, 19,  400000, N_PUB,   ROW_T, 64, ROW_P, 64,  7},  // tp
    { 4,  5, 1500000, N_VIDEO, ROW_U,  0, ROW_V,  0,  9},  // uv
    {14, 15,  800000, N_VIDEO, ROW_T,  0, ROW_V, 64,  9},  // tv
    { 6,  7, 1500000, N_USER,  ROW_V,  0, ROW_U,  0, 10},  // vu
    {10, 11,  800000, N_USER,  ROW_P,  0, ROW_U, 64, 10},  // pu
  };
  const float* dembs[8] = {emb_t, emb_t, emb_p, emb_p, emb_v, emb_v, emb_u, emb_u};

  char* ws = (char*)d_ws;
  size_t cursor = 0;
  auto take = [&](size_t bytes) -> char* {
    char* p = ws + cursor;
    cursor = (cursor + bytes + 255) & ~(size_t)255;
    return p;
  };
  uint16_t* featA = (uint16_t*)take((size_t)(ROWS + 1) * EMB * 2);
  uint16_t* featB = (uint16_t*)take((size_t)(ROWS + 1) * EMB * 2);
  int* sorted = (int*)take((size_t)SORT_MAX * 4);
  int* Beg    = (int*)take((size_t)TOTAL_GROUPS * 4);
  int* Deg    = (int*)take((size_t)TOTAL_GROUPS * 4);
  unsigned* pairs = (unsigned*)d_ws;   // alias over featA/featB (dead before convert)

  SortDesc sd;
  AggrDesc ad;
  int tacc = 0, bacc = 0, gacc = 0;
  for (int r = 0; r < 8; ++r) {
    int n_dst = rels[r].n_dst;
    sd.tcum[r] = tacc; tacc += (rels[r].E + TILE - 1) / TILE;
    sd.bcum[r] = bacc; bacc += (n_dst + (1 << rels[r].wshift) - 1) >> rels[r].wshift;
    sd.gcum[r] = gacc;
    sd.E[r] = rels[r].E;
    sd.n_dst[r] = n_dst;
    sd.wshift[r] = rels[r].wshift;
    sd.zrow[r] = ROWS - rels[r].src_base;
    sd.esrc[r] = (const int*)d_in[rels[r].si];
    sd.edst[r] = (const int*)d_in[rels[r].di];

    ad.cum[r] = gacc;
    ad.src_base[r] = rels[r].src_base;
    ad.src_col[r] = rels[r].src_col;
    ad.dst_base[r] = rels[r].dst_base;
    ad.dst_col[r] = rels[r].dst_col;
    ad.demb[r] = dembs[r];
    gacc += n_dst;
  }
  sd.tcum[8] = tacc;
  sd.bcum[8] = bacc;
  ad.cum[8] = gacc;    // 650000

  int* cursors  = (int*)take((size_t)bacc * 4 + 4);
  int* gcounter = cursors + bacc;

  // tier allocations (fp8 f1 buffer; standalone f2 buffer)
  const size_t f8bytes = (size_t)(ROWS + 1) * EMB;   // 41.6 MB
  size_t base_need = cursor;
  unsigned char* f1fp8 = nullptr;
  unsigned char* f2fp8 = (unsigned char*)featA;      // default: alias dead featA
  bool use_fp8_l1 = false;
  const uint16_t* demb_bf = nullptr;                 // tier 3: epilogue reads bf16 emb
  if (ws_size >= base_need + f8bytes + 256) {        // tier 2
    f1fp8 = (unsigned char*)take(f8bytes);
    use_fp8_l1 = true;
    if (ws_size >= cursor + f8bytes + 256) {         // tier 3: keep featA alive
      f2fp8 = (unsigned char*)take(f8bytes);
      demb_bf = featA;
    }
  }

  // ---- CSR build (padded to multiples of 8 per dst)
  hipMemsetAsync(cursors, 0, (size_t)(bacc + 1) * 4, stream);
  part_kernel<<<tacc, 256, 0, stream>>>(sd, pairs, cursors);
  build_kernel<<<bacc, 256, 0, stream>>>(sd, pairs, cursors, gcounter, sorted, Beg, Deg);

  // ---- bf16 feature init (pairs region dead) + zero rows
  convert_kernel<<<((ROWS + 1) * EMB / 8 + 255) / 256, 256, 0, stream>>>(
      emb_u, emb_v, emb_p, emb_t, featA, featB, f1fp8);

  float* out = (float*)d_out;
  const int aggr_blocks = (TOTAL_GROUPS + 31) / 32;
  if (use_fp8_l1) {
    // layer 0: featA(bf16) -> featB = f1 bf16  +  f1fp8 dual
    aggr_kernel<4><<<aggr_blocks, 256, 0, stream>>>(ad, featA, nullptr, featB, f1fp8,
                                                    nullptr, nullptr, nullptr, sorted, Beg, Deg);
    // layer 1: f1fp8 -> f2fp8 (fp8 gather, 64B/edge)
    aggr_kernel<1><<<aggr_blocks, 256, 0, stream>>>(ad, nullptr, f1fp8, nullptr, f2fp8,
                                                    nullptr, nullptr, nullptr, sorted, Beg, Deg);
  } else {
    aggr_kernel<0><<<aggr_blocks, 256, 0, stream>>>(ad, featA, nullptr, featB, nullptr,
                                                    nullptr, nullptr, nullptr, sorted, Beg, Deg);
    aggr_kernel<3><<<aggr_blocks, 256, 0, stream>>>(ad, featB, nullptr, nullptr, f2fp8,
                                                    nullptr, nullptr, nullptr, sorted, Beg, Deg);
  }
  // layer 2: gather f2fp8 -> f3; out = emb + 1/2 f1 + 1/3 f2 + 1/4 f3
  aggr_kernel<2><<<aggr_blocks, 256, 0, stream>>>(ad, nullptr, f2fp8, nullptr, nullptr,
                                                  featB, demb_bf, out, sorted, Beg, Deg);
}